// Round 6
// baseline (304.137 us; speedup 1.0000x reference)
//
#include <hip/hip_runtime.h>
#include <hip/hip_bf16.h>
#include <math.h>

#define NB_B 256
#define NB_S 50
#define NB_NB 8
#define NB_D 128
#define NB_NITEMS 100000

typedef __attribute__((ext_vector_type(8))) short short8;   // 8 x bf16 (4 VGPR)
typedef __attribute__((ext_vector_type(4))) float f32x4;    // MFMA acc
typedef unsigned int uint;
typedef unsigned short ushort;

__device__ __forceinline__ float wave_sum(float t) {
#pragma unroll
  for (int off = 32; off; off >>= 1) t += __shfl_xor(t, off);
  return t;
}

__device__ __forceinline__ float sigf(float x) { return 1.f / (1.f + __expf(-x)); }

// fp32 -> bf16 round-to-nearest-even
__device__ __forceinline__ ushort f2bf(float f) {
  union { float f; uint u; } v;
  v.f = f;
  return (ushort)((v.u + 0x7fffu + ((v.u >> 16) & 1u)) >> 16);
}
__device__ __forceinline__ uint packbf(float a, float b) {
  return (uint)f2bf(a) | ((uint)f2bf(b) << 16);
}
__device__ __forceinline__ float bflo(uint u) {
  union { uint u; float f; } v; v.u = u << 16; return v.f;
}
__device__ __forceinline__ float bfhi(uint u) {
  union { uint u; float f; } v; v.u = u & 0xffff0000u; return v.f;
}

// ---------------- elementwise fp32 -> packed bf16 (8 floats / thread) ----------------
__global__ __launch_bounds__(256) void castf_kernel(const float* __restrict__ src,
                                                    uint* __restrict__ dst, int n8) {
  int i = blockIdx.x * 256 + threadIdx.x;
  if (i >= n8) return;
  float4 a = ((const float4*)src)[2 * i];
  float4 b = ((const float4*)src)[2 * i + 1];
  uint4 o;
  o.x = packbf(a.x, a.y);
  o.y = packbf(a.z, a.w);
  o.z = packbf(b.x, b.y);
  o.w = packbf(b.z, b.w);
  ((uint4*)dst)[i] = o;
}

// ---------------- W[K][CO] -> WT bf16 [CO][K] ----------------
template <int K, int CO>
__global__ __launch_bounds__(256) void castT_kernel(const float* __restrict__ W,
                                                    ushort* __restrict__ WT) {
  int idx = blockIdx.x * 256 + threadIdx.x;
  if (idx >= K * CO) return;
  int n = idx / K, k = idx % K;
  WT[idx] = f2bf(W[(size_t)k * CO + n]);
}

// ---------------- hop aggregation (bf16 tables, packed pairs) ----------------
template <int LEVEL>
__global__ __launch_bounds__(256) void hop_kernel(
    const int* __restrict__ h_iids, const int* __restrict__ adj_e,
    const int* __restrict__ adj_r, const uint* __restrict__ embB,
    const uint* __restrict__ relB, const uint* __restrict__ neibB,
    const float* __restrict__ Wa, uint* __restrict__ Xout, int npairs) {
  int p = (int)((blockIdx.x * blockDim.x + threadIdx.x) >> 6);
  p = __builtin_amdgcn_readfirstlane(p);
  int ln = threadIdx.x & 63;
  if (p >= npairs) return;

  int e_self;
  if (LEVEL == 0) {
    int b = p / (NB_S * NB_NB);
    int m = p % (NB_S * NB_NB);
    int s = m >> 3, j = m & 7;
    int h = h_iids[b * NB_S + s];
    e_self = adj_e[h * NB_NB + j];
  } else {
    e_self = h_iids[p];
  }

  float wa0 = Wa[2 * ln], wa1 = Wa[2 * ln + 1];
  uint us = embB[(size_t)e_self * 64 + ln];
  float s0 = bflo(us), s1 = bfhi(us);

  float nb0[NB_NB], nb1[NB_NB], att[NB_NB];
#pragma unroll
  for (int k = 0; k < NB_NB; k++) {
    int r = adj_r[e_self * NB_NB + k];
    uint un;
    if (LEVEL == 0) {
      int e2 = adj_e[e_self * NB_NB + k];
      un = embB[(size_t)e2 * 64 + ln];
    } else {
      un = neibB[((size_t)p * NB_NB + k) * 64 + ln];
    }
    uint ur = relB[r * 64 + ln];
    nb0[k] = bflo(un);
    nb1[k] = bfhi(un);
    float t = s0 * bflo(ur) * nb0[k] * wa0 + s1 * bfhi(ur) * nb1[k] * wa1;
    att[k] = wave_sum(t);
  }
  // |att| <= ~0.04 -> exp safe without max-subtraction (softmax-invariant)
  float den = 0.f, ex[NB_NB];
#pragma unroll
  for (int k = 0; k < NB_NB; k++) { ex[k] = __expf(att[k]); den += ex[k]; }
  float inv = 1.f / den;
  float x0 = s0, x1 = s1;
#pragma unroll
  for (int k = 0; k < NB_NB; k++) {
    float a = ex[k] * inv;
    x0 += a * nb0[k];
    x1 += a * nb1[k];
  }
  Xout[(size_t)p * 64 + ln] = packbf(x0, x1);
}

// ---------------- Y[N,CO] = Xbf[N,128] @ WT_bf^T + bias  (MFMA, no LDS) ----------------
template <int CO, int MPW, bool OUT_BF>
__global__ __launch_bounds__(256) void linm_kernel(
    const ushort* __restrict__ Xbf, const ushort* __restrict__ WT,
    const float* __restrict__ bias, float* __restrict__ Yf,
    ushort* __restrict__ Yb, int nrows) {
  constexpr int NF = CO / 16;
  constexpr int MF = MPW / 16;
  int wave = (int)(blockIdx.x * 4 + (threadIdx.x >> 6));
  int ln = threadIdx.x & 63;
  int m0 = __builtin_amdgcn_readfirstlane(wave) * MPW;
  if (m0 >= nrows) return;
  int lr = ln & 15, lg = ln >> 4;

  short8 afr[MF][4];
#pragma unroll
  for (int mf = 0; mf < MF; mf++) {
    const ushort* ab = Xbf + (size_t)(m0 + mf * 16 + lr) * 128 + lg * 8;
#pragma unroll
    for (int kf = 0; kf < 4; kf++) afr[mf][kf] = *(const short8*)(ab + kf * 32);
  }
  f32x4 acc[MF][NF] = {};
#pragma unroll
  for (int nf = 0; nf < NF; nf++) {
    const ushort* bb = WT + (size_t)(nf * 16 + lr) * 128 + lg * 8;
#pragma unroll
    for (int kf = 0; kf < 4; kf++) {
      short8 b = *(const short8*)(bb + kf * 32);
#pragma unroll
      for (int mf = 0; mf < MF; mf++)
        acc[mf][nf] = __builtin_amdgcn_mfma_f32_16x16x32_bf16(afr[mf][kf], b,
                                                              acc[mf][nf], 0, 0, 0);
    }
  }
#pragma unroll
  for (int mf = 0; mf < MF; mf++)
#pragma unroll
    for (int nf = 0; nf < NF; nf++) {
      int n = nf * 16 + lr;
      float bv = bias[n];
#pragma unroll
      for (int r = 0; r < 4; r++) {
        int m = m0 + mf * 16 + lg * 4 + r;
        float val = acc[mf][nf][r] + bv;
        if (OUT_BF)
          Yb[(size_t)m * CO + n] = f2bf(val);
        else
          Yf[(size_t)m * CO + n] = val;
      }
    }
}

// ---------------- GRU via batched MFMA recurrence ----------------
// 16 blocks x 512 threads; block owns 16 batch rows. Per step:
//   GH[16][384] = bf16(h)[16][128] @ WhhT_bf  (MFMA, Whh frags in registers)
//   gates on 512 threads (4 (b,j) pairs each), fp32 identity path in registers.
// NOTE: n-gate is tanh(inn + r*(gh_n + bhh_n)) -- bhh_n goes INSIDE the r* term.
__global__ __launch_bounds__(512) void gru_mfma_kernel(
    const float* __restrict__ GI, const ushort* __restrict__ WhhT_bf,
    const float* __restrict__ bhh, float* __restrict__ OUT) {
  const int b0 = blockIdx.x * 16;
  const int tid = threadIdx.x;
  const int w = tid >> 6, ln = tid & 63;
  const int lr = ln & 15, lg = ln >> 4;

  __shared__ ushort h_bf[16 * 128];  // XOR-swizzled bf16 h (MFMA A operand)
  __shared__ float GH[16][388];      // padded stride: 2-way max on MFMA stores

  // B-frags: wave w covers n in [w*48, w*48+48)
  short8 bfr[3][4];
#pragma unroll
  for (int nf = 0; nf < 3; nf++) {
    const ushort* bb = WhhT_bf + (size_t)(w * 48 + nf * 16 + lr) * 128 + lg * 8;
#pragma unroll
    for (int kf = 0; kf < 4; kf++) bfr[nf][kf] = *(const short8*)(bb + kf * 32);
  }

  // per-thread gate state: 4 pairs q = tid + s*512 -> (b=q>>7, j=q&127)
  float h_reg[4] = {0.f, 0.f, 0.f, 0.f};
  float bh_r[4], bh_z[4], bh_n[4];
#pragma unroll
  for (int s = 0; s < 4; s++) {
    int j = (tid + s * 512) & 127;
    bh_r[s] = bhh[j];
    bh_z[s] = bhh[128 + j];
    bh_n[s] = bhh[256 + j];
  }

  // h_bf = 0
  {
    uint* hz = (uint*)h_bf;
#pragma unroll
    for (int i = tid; i < 1024; i += 512) hz[i] = 0;
  }
  __syncthreads();

  // GI prefetch for t=0
  float gir[4][3];
#pragma unroll
  for (int s = 0; s < 4; s++) {
    int q = tid + s * 512, b = q >> 7, j = q & 127;
    const float* g = GI + ((size_t)(b0 + b) * NB_S + 0) * 384;
    gir[s][0] = g[j]; gir[s][1] = g[128 + j]; gir[s][2] = g[256 + j];
  }

  for (int t = 0; t < NB_S; t++) {
    // A-frags from swizzled h_bf
    short8 afr[4];
#pragma unroll
    for (int kf = 0; kf < 4; kf++) {
      int byte = (lr * 256 + kf * 64 + lg * 16) ^ ((lr & 7) << 4);
      afr[kf] = *(const short8*)((const char*)h_bf + byte);
    }
    f32x4 acc[3] = {};
#pragma unroll
    for (int nf = 0; nf < 3; nf++)
#pragma unroll
      for (int kf = 0; kf < 4; kf++)
        acc[nf] = __builtin_amdgcn_mfma_f32_16x16x32_bf16(afr[kf], bfr[nf][kf],
                                                          acc[nf], 0, 0, 0);
#pragma unroll
    for (int nf = 0; nf < 3; nf++)
#pragma unroll
      for (int r = 0; r < 4; r++)
        GH[lg * 4 + r][w * 48 + nf * 16 + lr] = acc[nf][r];

    // prefetch GI for t+1 (overlaps with barrier/gates)
    float gir2[4][3];
    if (t + 1 < NB_S) {
#pragma unroll
      for (int s = 0; s < 4; s++) {
        int q = tid + s * 512, b = q >> 7, j = q & 127;
        const float* g = GI + ((size_t)(b0 + b) * NB_S + (t + 1)) * 384;
        gir2[s][0] = g[j]; gir2[s][1] = g[128 + j]; gir2[s][2] = g[256 + j];
      }
    }
    __syncthreads();

    // gates
#pragma unroll
    for (int s = 0; s < 4; s++) {
      int q = tid + s * 512, b = q >> 7, j = q & 127;
      float r = sigf(gir[s][0] + bh_r[s] + GH[b][j]);
      float z = sigf(gir[s][1] + bh_z[s] + GH[b][128 + j]);
      float x = gir[s][2] + r * (bh_n[s] + GH[b][256 + j]);  // bias INSIDE r*
      float e2 = __expf(2.f * x);
      float n = 1.f - 2.f / (e2 + 1.f);  // tanh(x)
      float h2 = (1.f - z) * n + z * h_reg[s];
      h_reg[s] = h2;
      OUT[((size_t)(b0 + b) * NB_S + t) * 128 + j] = h2;
      int byte = ((b * 128 + j) * 2) ^ ((b & 7) << 4);
      *(ushort*)((char*)h_bf + byte) = f2bf(h2);
    }
#pragma unroll
    for (int s = 0; s < 4; s++) {
      gir[s][0] = gir2[s][0]; gir[s][1] = gir2[s][1]; gir[s][2] = gir2[s][2];
    }
    __syncthreads();
  }
}

// ---------------- pooling ----------------
__global__ __launch_bounds__(128) void pool_a_kernel(
    const int* __restrict__ h_iids, const float* __restrict__ OUT,
    const float* __restrict__ W1, const float* __restrict__ b1,
    float* __restrict__ LOCAL, float* __restrict__ Q1) {
  int b = blockIdx.x, c = threadIdx.x;
  int cnt = 0;
  for (int s = 0; s < NB_S; s++) cnt += (h_iids[b * NB_S + s] != 0);
  int li = min(max(cnt - 1, 0), NB_S - 1);
  __shared__ float lh[128];
  float lv = OUT[((size_t)b * NB_S + li) * 128 + c];
  lh[c] = lv;
  LOCAL[b * 128 + c] = lv;
  __syncthreads();
  float acc = b1[c];
  for (int d = 0; d < 128; d++) acc += lh[d] * W1[(size_t)d * 128 + c];
  Q1[b * 128 + c] = acc;
}

__global__ __launch_bounds__(256) void pool_b_kernel(
    const float* __restrict__ OUT, const float* __restrict__ W2,
    const float* __restrict__ b2, const float* __restrict__ W3,
    const float* __restrict__ Q1, float* __restrict__ AL) {
  int p = (int)((blockIdx.x * blockDim.x + threadIdx.x) >> 6);
  p = __builtin_amdgcn_readfirstlane(p);
  int ln = threadIdx.x & 63;
  if (p >= NB_B * NB_S) return;
  int b = p / NB_S;
  const float* x = OUT + (size_t)p * 128;
  float acc0 = b2[ln], acc1 = b2[64 + ln];
  for (int d = 0; d < 128; d++) {
    float xv = x[d];
    acc0 += xv * W2[(size_t)d * 128 + ln];
    acc1 += xv * W2[(size_t)d * 128 + 64 + ln];
  }
  float t = sigf(Q1[b * 128 + ln] + acc0) * W3[ln] +
            sigf(Q1[b * 128 + 64 + ln] + acc1) * W3[64 + ln];
  t = wave_sum(t);
  if (ln == 0) AL[p] = t;
}

__global__ __launch_bounds__(128) void pool_c_kernel(
    const float* __restrict__ OUT, const float* __restrict__ AL,
    const float* __restrict__ LOCAL, const float* __restrict__ Wtr,
    const float* __restrict__ btr, ushort* __restrict__ GHT_bf) {
  int b = blockIdx.x, d = threadIdx.x;
  float g = 0.f;
  for (int s = 0; s < NB_S; s++)
    g += AL[b * NB_S + s] * OUT[((size_t)b * NB_S + s) * 128 + d];
  __shared__ float cat[256];
  cat[d] = LOCAL[b * 128 + d];
  cat[128 + d] = g;
  __syncthreads();
  float acc = btr[d];
  for (int dd = 0; dd < 256; dd++) acc += cat[dd] * Wtr[(size_t)dd * 128 + d];
  GHT_bf[b * 128 + d] = f2bf(acc);
}

// ---------------- logits = relu(GHT_bf @ EMB_BF^T) via MFMA ----------------
__global__ __launch_bounds__(256) void logits_mfma_kernel(
    const ushort* __restrict__ GHT_bf, const ushort* __restrict__ embB,
    float* __restrict__ out) {
  int wave = (int)(blockIdx.x * 4 + (threadIdx.x >> 6));
  int ln = threadIdx.x & 63;
  int n0 = __builtin_amdgcn_readfirstlane(wave) * 32;
  if (n0 >= NB_NITEMS) return;
  int lr = ln & 15, lg = ln >> 4;

  short8 bfr[2][4];
#pragma unroll
  for (int nf = 0; nf < 2; nf++) {
    const ushort* base = embB + (size_t)(n0 + nf * 16 + lr) * 128 + lg * 8;
#pragma unroll
    for (int kf = 0; kf < 4; kf++) bfr[nf][kf] = *(const short8*)(base + kf * 32);
  }

  f32x4 acc[16][2] = {};
#pragma unroll
  for (int mg = 0; mg < 4; mg++) {
    short8 afr[4][4];
#pragma unroll
    for (int mf = 0; mf < 4; mf++) {
      const ushort* ab = GHT_bf + (size_t)((mg * 4 + mf) * 16 + lr) * 128 + lg * 8;
#pragma unroll
      for (int kf = 0; kf < 4; kf++) afr[mf][kf] = *(const short8*)(ab + kf * 32);
    }
#pragma unroll
    for (int mf = 0; mf < 4; mf++)
#pragma unroll
      for (int nf = 0; nf < 2; nf++)
#pragma unroll
        for (int kf = 0; kf < 4; kf++)
          acc[mg * 4 + mf][nf] = __builtin_amdgcn_mfma_f32_16x16x32_bf16(
              afr[mf][kf], bfr[nf][kf], acc[mg * 4 + mf][nf], 0, 0, 0);
  }

#pragma unroll
  for (int mf = 0; mf < 16; mf++)
#pragma unroll
    for (int nf = 0; nf < 2; nf++) {
      int n = n0 + nf * 16 + lr;
#pragma unroll
      for (int r = 0; r < 4; r++) {
        int m = mf * 16 + lg * 4 + r;
        out[(size_t)m * NB_NITEMS + n] = fmaxf(acc[mf][nf][r], 0.f);
      }
    }
}

extern "C" void kernel_launch(void* const* d_in, const int* in_sizes, int n_in,
                              void* d_out, int out_size, void* d_ws, size_t ws_size,
                              hipStream_t stream) {
  const int* h_iids = (const int*)d_in[0];
  const int* adj_e = (const int*)d_in[2];
  const int* adj_r = (const int*)d_in[3];
  const float* item_emb = (const float*)d_in[4];
  const float* rel_emb = (const float*)d_in[5];
  const float* Wa = (const float*)d_in[6];
  const float* Wt = (const float*)d_in[8];
  const float* bt = (const float*)d_in[9];
  const float* Wih = (const float*)d_in[10];
  const float* Whh = (const float*)d_in[11];
  const float* bih = (const float*)d_in[12];
  const float* bhh = (const float*)d_in[13];
  const float* W1 = (const float*)d_in[14];
  const float* b1 = (const float*)d_in[15];
  const float* W2 = (const float*)d_in[16];
  const float* b2 = (const float*)d_in[17];
  const float* W3 = (const float*)d_in[18];
  const float* Wtr = (const float*)d_in[19];
  const float* btr = (const float*)d_in[20];
  float* out = (float*)d_out;

  // ws layout (bytes), all 16B-aligned. ~85.2 MB total.
  char* w = (char*)d_ws;
  uint* EMB_BF = (uint*)w;                    w += 25600000;  // 100000x128 bf16
  uint* REL_BF = (uint*)w;                    w += 51200;     // 200x128 bf16
  ushort* WtT_bf = (ushort*)w;                w += 32768;     // [128][128]
  ushort* WihT_bf = (ushort*)w;               w += 98304;     // [384][128]
  ushort* WhhT_bf = (ushort*)w;               w += 98304;     // [384][128]
  uint* NEIB_bf = (uint*)w;                   w += 26214400;  // 102400x128 bf16
  uint* X1_bf = (uint*)w;                     w += 3276800;   // 12800x128 bf16
  uint* SEQ_bf = (uint*)w;                    w += 3276800;   // 12800x128 bf16
  float* GI = (float*)w;                      w += 19660800;  // 12800x384 fp32
  float* GOUT = (float*)w;                    w += 6553600;   // 12800x128 fp32
  float* LOCAL = (float*)w;                   w += 131072;
  float* Q1 = (float*)w;                      w += 131072;
  float* AL = (float*)w;                      w += 51200;
  ushort* GHT_bf = (ushort*)w;                w += 65536;

  // X0 (bf16 packed, 26.2MB) borrows d_out (102.4MB); logits fully overwrites it.
  uint* X0_bf = (uint*)d_out;

  // ---- prep casts ----
  castf_kernel<<<6250, 256, 0, stream>>>(item_emb, EMB_BF, 1600000);
  castf_kernel<<<13, 256, 0, stream>>>(rel_emb, REL_BF, 3200);
  castT_kernel<128, 128><<<64, 256, 0, stream>>>(Wt, WtT_bf);
  castT_kernel<128, 384><<<192, 256, 0, stream>>>(Wih, WihT_bf);
  castT_kernel<128, 384><<<192, 256, 0, stream>>>(Whh, WhhT_bf);

  // ---- KG hops ----
  hop_kernel<0><<<25600, 256, 0, stream>>>(h_iids, adj_e, adj_r, EMB_BF, REL_BF,
                                           nullptr, Wa, X0_bf, 102400);
  linm_kernel<128, 32, true><<<800, 256, 0, stream>>>(
      (const ushort*)X0_bf, WtT_bf, bt, nullptr, (ushort*)NEIB_bf, 102400);
  hop_kernel<1><<<3200, 256, 0, stream>>>(h_iids, adj_e, adj_r, EMB_BF, REL_BF,
                                          NEIB_bf, Wa, X1_bf, 12800);
  linm_kernel<128, 32, true><<<100, 256, 0, stream>>>(
      (const ushort*)X1_bf, WtT_bf, bt, nullptr, (ushort*)SEQ_bf, 12800);
  linm_kernel<384, 16, false><<<200, 256, 0, stream>>>(
      (const ushort*)SEQ_bf, WihT_bf, bih, GI, nullptr, 12800);

  // ---- GRU + pooling ----
  gru_mfma_kernel<<<16, 512, 0, stream>>>(GI, WhhT_bf, bhh, GOUT);
  pool_a_kernel<<<256, 128, 0, stream>>>(h_iids, GOUT, W1, b1, LOCAL, Q1);
  pool_b_kernel<<<3200, 256, 0, stream>>>(GOUT, W2, b2, W3, Q1, AL);
  pool_c_kernel<<<256, 128, 0, stream>>>(GOUT, AL, LOCAL, Wtr, btr, GHT_bf);

  // ---- logits ----
  logits_mfma_kernel<<<782, 256, 0, stream>>>(GHT_bf, (const ushort*)EMB_BF, out);
}

// Round 7
// 296.798 us; speedup vs baseline: 1.0247x; 1.0247x over previous
//
#include <hip/hip_runtime.h>
#include <hip/hip_bf16.h>
#include <math.h>

#define NB_B 256
#define NB_S 50
#define NB_NB 8
#define NB_D 128
#define NB_NITEMS 100000

typedef __attribute__((ext_vector_type(8))) short short8;   // 8 x bf16 (4 VGPR)
typedef __attribute__((ext_vector_type(4))) float f32x4;    // MFMA acc
typedef unsigned int uint;
typedef unsigned short ushort;

__device__ __forceinline__ float wave_sum(float t) {
#pragma unroll
  for (int off = 32; off; off >>= 1) t += __shfl_xor(t, off);
  return t;
}

__device__ __forceinline__ float sigf(float x) { return 1.f / (1.f + __expf(-x)); }

// fp32 -> bf16 round-to-nearest-even
__device__ __forceinline__ ushort f2bf(float f) {
  union { float f; uint u; } v;
  v.f = f;
  return (ushort)((v.u + 0x7fffu + ((v.u >> 16) & 1u)) >> 16);
}
__device__ __forceinline__ uint packbf(float a, float b) {
  return (uint)f2bf(a) | ((uint)f2bf(b) << 16);
}
__device__ __forceinline__ float bflo(uint u) {
  union { uint u; float f; } v; v.u = u << 16; return v.f;
}
__device__ __forceinline__ float bfhi(uint u) {
  union { uint u; float f; } v; v.u = u & 0xffff0000u; return v.f;
}

// ---------------- elementwise fp32 -> packed bf16 (8 floats / thread) ----------------
__global__ __launch_bounds__(256) void castf_kernel(const float* __restrict__ src,
                                                    uint* __restrict__ dst, int n8) {
  int i = blockIdx.x * 256 + threadIdx.x;
  if (i >= n8) return;
  float4 a = ((const float4*)src)[2 * i];
  float4 b = ((const float4*)src)[2 * i + 1];
  uint4 o;
  o.x = packbf(a.x, a.y);
  o.y = packbf(a.z, a.w);
  o.z = packbf(b.x, b.y);
  o.w = packbf(b.z, b.w);
  ((uint4*)dst)[i] = o;
}

// ---------------- W[K][CO] -> WT bf16 [CO][K] ----------------
template <int K, int CO>
__global__ __launch_bounds__(256) void castT_kernel(const float* __restrict__ W,
                                                    ushort* __restrict__ WT) {
  int idx = blockIdx.x * 256 + threadIdx.x;
  if (idx >= K * CO) return;
  int n = idx / K, k = idx % K;
  WT[idx] = f2bf(W[(size_t)k * CO + n]);
}

// ---------------- hop aggregation (bf16 tables, packed pairs) ----------------
template <int LEVEL>
__global__ __launch_bounds__(256) void hop_kernel(
    const int* __restrict__ h_iids, const int* __restrict__ adj_e,
    const int* __restrict__ adj_r, const uint* __restrict__ embB,
    const uint* __restrict__ relB, const uint* __restrict__ neibB,
    const float* __restrict__ Wa, uint* __restrict__ Xout, int npairs) {
  int p = (int)((blockIdx.x * blockDim.x + threadIdx.x) >> 6);
  p = __builtin_amdgcn_readfirstlane(p);
  int ln = threadIdx.x & 63;
  if (p >= npairs) return;

  int e_self;
  if (LEVEL == 0) {
    int b = p / (NB_S * NB_NB);
    int m = p % (NB_S * NB_NB);
    int s = m >> 3, j = m & 7;
    int h = h_iids[b * NB_S + s];
    e_self = adj_e[h * NB_NB + j];
  } else {
    e_self = h_iids[p];
  }

  float wa0 = Wa[2 * ln], wa1 = Wa[2 * ln + 1];
  uint us = embB[(size_t)e_self * 64 + ln];
  float s0 = bflo(us), s1 = bfhi(us);

  float nb0[NB_NB], nb1[NB_NB], att[NB_NB];
#pragma unroll
  for (int k = 0; k < NB_NB; k++) {
    int r = adj_r[e_self * NB_NB + k];
    uint un;
    if (LEVEL == 0) {
      int e2 = adj_e[e_self * NB_NB + k];
      un = embB[(size_t)e2 * 64 + ln];
    } else {
      un = neibB[((size_t)p * NB_NB + k) * 64 + ln];
    }
    uint ur = relB[r * 64 + ln];
    nb0[k] = bflo(un);
    nb1[k] = bfhi(un);
    float t = s0 * bflo(ur) * nb0[k] * wa0 + s1 * bfhi(ur) * nb1[k] * wa1;
    att[k] = wave_sum(t);
  }
  // |att| <= ~0.04 -> exp safe without max-subtraction (softmax-invariant)
  float den = 0.f, ex[NB_NB];
#pragma unroll
  for (int k = 0; k < NB_NB; k++) { ex[k] = __expf(att[k]); den += ex[k]; }
  float inv = 1.f / den;
  float x0 = s0, x1 = s1;
#pragma unroll
  for (int k = 0; k < NB_NB; k++) {
    float a = ex[k] * inv;
    x0 += a * nb0[k];
    x1 += a * nb1[k];
  }
  Xout[(size_t)p * 64 + ln] = packbf(x0, x1);
}

// ---------------- Y[N,CO] = Xbf[N,128] @ WT_bf^T + bias  (MFMA, no LDS) ----------------
template <int CO, int MPW, bool OUT_BF>
__global__ __launch_bounds__(256) void linm_kernel(
    const ushort* __restrict__ Xbf, const ushort* __restrict__ WT,
    const float* __restrict__ bias, float* __restrict__ Yf,
    ushort* __restrict__ Yb, int nrows) {
  constexpr int NF = CO / 16;
  constexpr int MF = MPW / 16;
  int wave = (int)(blockIdx.x * 4 + (threadIdx.x >> 6));
  int ln = threadIdx.x & 63;
  int m0 = __builtin_amdgcn_readfirstlane(wave) * MPW;
  if (m0 >= nrows) return;
  int lr = ln & 15, lg = ln >> 4;

  short8 afr[MF][4];
#pragma unroll
  for (int mf = 0; mf < MF; mf++) {
    const ushort* ab = Xbf + (size_t)(m0 + mf * 16 + lr) * 128 + lg * 8;
#pragma unroll
    for (int kf = 0; kf < 4; kf++) afr[mf][kf] = *(const short8*)(ab + kf * 32);
  }
  f32x4 acc[MF][NF] = {};
#pragma unroll
  for (int nf = 0; nf < NF; nf++) {
    const ushort* bb = WT + (size_t)(nf * 16 + lr) * 128 + lg * 8;
#pragma unroll
    for (int kf = 0; kf < 4; kf++) {
      short8 b = *(const short8*)(bb + kf * 32);
#pragma unroll
      for (int mf = 0; mf < MF; mf++)
        acc[mf][nf] = __builtin_amdgcn_mfma_f32_16x16x32_bf16(afr[mf][kf], b,
                                                              acc[mf][nf], 0, 0, 0);
    }
  }
#pragma unroll
  for (int mf = 0; mf < MF; mf++)
#pragma unroll
    for (int nf = 0; nf < NF; nf++) {
      int n = nf * 16 + lr;
      float bv = bias[n];
#pragma unroll
      for (int r = 0; r < 4; r++) {
        int m = m0 + mf * 16 + lg * 4 + r;
        float val = acc[mf][nf][r] + bv;
        if (OUT_BF)
          Yb[(size_t)m * CO + n] = f2bf(val);
        else
          Yf[(size_t)m * CO + n] = val;
      }
    }
}

// ---------------- GRU via batched MFMA recurrence, raw-barrier pipelined ----------------
// 16 blocks x 512 threads; block owns 16 batch rows.
// Barriers are raw s_barrier with LDS-only drain (s_waitcnt lgkmcnt(0)) so the
// GI prefetch stays in flight for a full step (the __syncthreads vmcnt(0) drain
// was the 75us bottleneck). t-loop unrolled by 2 with named girA/girB buffers.
// NOTE: n-gate is tanh(inn + r*(gh_n + bhh_n)) -- bhh_n INSIDE the r* term.
__global__ __launch_bounds__(512) void gru_mfma_kernel(
    const float* __restrict__ GI, const ushort* __restrict__ WhhT_bf,
    const float* __restrict__ bhh, float* __restrict__ OUT,
    ushort* __restrict__ OUTB) {
  const int b0 = blockIdx.x * 16;
  const int tid = threadIdx.x;
  const int w = tid >> 6, ln = tid & 63;
  const int lr = ln & 15, lg = ln >> 4;

  __shared__ ushort h_bf[16 * 128];  // XOR-swizzled bf16 h (MFMA A operand)
  __shared__ float GH[16][388];      // padded stride

  // B-frags: wave w covers n in [w*48, w*48+48)
  short8 bfr[3][4];
#pragma unroll
  for (int nf = 0; nf < 3; nf++) {
    const ushort* bb = WhhT_bf + (size_t)(w * 48 + nf * 16 + lr) * 128 + lg * 8;
#pragma unroll
    for (int kf = 0; kf < 4; kf++) bfr[nf][kf] = *(const short8*)(bb + kf * 32);
  }

  float h_reg[4] = {0.f, 0.f, 0.f, 0.f};
  float bh_r[4], bh_z[4], bh_n[4];
#pragma unroll
  for (int s = 0; s < 4; s++) {
    int j = (tid + s * 512) & 127;
    bh_r[s] = bhh[j];
    bh_z[s] = bhh[128 + j];
    bh_n[s] = bhh[256 + j];
  }

  {
    uint* hz = (uint*)h_bf;
#pragma unroll
    for (int i = tid; i < 1024; i += 512) hz[i] = 0;
  }
  __syncthreads();

  float girA[4][3], girB[4][3];
#pragma unroll
  for (int s = 0; s < 4; s++) {
    int q = tid + s * 512, b = q >> 7, j = q & 127;
    const float* g = GI + ((size_t)(b0 + b) * NB_S + 0) * 384;
    girA[s][0] = g[j]; girA[s][1] = g[128 + j]; girA[s][2] = g[256 + j];
  }

  auto STEP = [&](int t, float (&cur)[4][3], float (&nxt)[4][3]) {
    // A-frags from swizzled h_bf
    short8 afr[4];
#pragma unroll
    for (int kf = 0; kf < 4; kf++) {
      int byte = (lr * 256 + kf * 64 + lg * 16) ^ ((lr & 7) << 4);
      afr[kf] = *(const short8*)((const char*)h_bf + byte);
    }
    f32x4 acc[3] = {};
#pragma unroll
    for (int nf = 0; nf < 3; nf++)
#pragma unroll
      for (int kf = 0; kf < 4; kf++)
        acc[nf] = __builtin_amdgcn_mfma_f32_16x16x32_bf16(afr[kf], bfr[nf][kf],
                                                          acc[nf], 0, 0, 0);
#pragma unroll
    for (int nf = 0; nf < 3; nf++)
#pragma unroll
      for (int r = 0; r < 4; r++)
        GH[lg * 4 + r][w * 48 + nf * 16 + lr] = acc[nf][r];

    // prefetch GI for t+1; consumed NEXT step -> in flight a full step
    if (t + 1 < NB_S) {
#pragma unroll
      for (int s = 0; s < 4; s++) {
        int q = tid + s * 512, b = q >> 7, j = q & 127;
        const float* g = GI + ((size_t)(b0 + b) * NB_S + (t + 1)) * 384;
        nxt[s][0] = g[j]; nxt[s][1] = g[128 + j]; nxt[s][2] = g[256 + j];
      }
    }
    asm volatile("s_waitcnt lgkmcnt(0)" ::: "memory");
    __builtin_amdgcn_s_barrier();  // GH visible; GI loads NOT drained

    // gates
#pragma unroll
    for (int s = 0; s < 4; s++) {
      int q = tid + s * 512, b = q >> 7, j = q & 127;
      float r = sigf(cur[s][0] + bh_r[s] + GH[b][j]);
      float z = sigf(cur[s][1] + bh_z[s] + GH[b][128 + j]);
      float x = cur[s][2] + r * (bh_n[s] + GH[b][256 + j]);  // bias INSIDE r*
      float e2 = __expf(2.f * x);
      float n = 1.f - 2.f / (e2 + 1.f);  // tanh(x)
      float h2 = (1.f - z) * n + z * h_reg[s];
      h_reg[s] = h2;
      size_t o = ((size_t)(b0 + b) * NB_S + t) * 128 + j;
      OUT[o] = h2;
      ushort hb = f2bf(h2);
      OUTB[o] = hb;
      int byte = ((b * 128 + j) * 2) ^ ((b & 7) << 4);
      *(ushort*)((char*)h_bf + byte) = hb;
    }
    asm volatile("s_waitcnt lgkmcnt(0)" ::: "memory");
    __builtin_amdgcn_s_barrier();  // h_bf visible
  };

  for (int t2 = 0; t2 < NB_S; t2 += 2) {
    STEP(t2, girA, girB);
    STEP(t2 + 1, girB, girA);
  }
}

// ---------------- pooling ----------------
__global__ __launch_bounds__(128) void pool_a_kernel(
    const int* __restrict__ h_iids, const float* __restrict__ OUT,
    const float* __restrict__ W1, const float* __restrict__ b1,
    float* __restrict__ LOCAL, float* __restrict__ Q1) {
  int b = blockIdx.x, c = threadIdx.x;
  int cnt = 0;
  for (int s = 0; s < NB_S; s++) cnt += (h_iids[b * NB_S + s] != 0);
  int li = min(max(cnt - 1, 0), NB_S - 1);
  __shared__ float lh[128];
  float lv = OUT[((size_t)b * NB_S + li) * 128 + c];
  lh[c] = lv;
  LOCAL[b * 128 + c] = lv;
  __syncthreads();
  float acc = b1[c];
  for (int d = 0; d < 128; d++) acc += lh[d] * W1[(size_t)d * 128 + c];
  Q1[b * 128 + c] = acc;
}

// AL[p] = sum_n sigmoid(Q1[b][n] + Q2[p][n]) * W3[n]
__global__ __launch_bounds__(256) void pool_b2_kernel(
    const float* __restrict__ Q2, const float* __restrict__ Q1,
    const float* __restrict__ W3, float* __restrict__ AL) {
  int p = (int)((blockIdx.x * blockDim.x + threadIdx.x) >> 6);
  p = __builtin_amdgcn_readfirstlane(p);
  int ln = threadIdx.x & 63;
  if (p >= NB_B * NB_S) return;
  int b = p / NB_S;
  float t = sigf(Q1[b * 128 + ln] + Q2[(size_t)p * 128 + ln]) * W3[ln] +
            sigf(Q1[b * 128 + 64 + ln] + Q2[(size_t)p * 128 + 64 + ln]) * W3[64 + ln];
  t = wave_sum(t);
  if (ln == 0) AL[p] = t;
}

__global__ __launch_bounds__(128) void pool_c_kernel(
    const float* __restrict__ OUT, const float* __restrict__ AL,
    const float* __restrict__ LOCAL, const float* __restrict__ Wtr,
    const float* __restrict__ btr, ushort* __restrict__ GHT_bf) {
  int b = blockIdx.x, d = threadIdx.x;
  float g = 0.f;
  for (int s = 0; s < NB_S; s++)
    g += AL[b * NB_S + s] * OUT[((size_t)b * NB_S + s) * 128 + d];
  __shared__ float cat[256];
  cat[d] = LOCAL[b * 128 + d];
  cat[128 + d] = g;
  __syncthreads();
  float acc = btr[d];
  for (int dd = 0; dd < 256; dd++) acc += cat[dd] * Wtr[(size_t)dd * 128 + d];
  GHT_bf[b * 128 + d] = f2bf(acc);
}

// ---------------- logits = relu(GHT_bf @ EMB_BF^T) via MFMA ----------------
__global__ __launch_bounds__(256) void logits_mfma_kernel(
    const ushort* __restrict__ GHT_bf, const ushort* __restrict__ embB,
    float* __restrict__ out) {
  int wave = (int)(blockIdx.x * 4 + (threadIdx.x >> 6));
  int ln = threadIdx.x & 63;
  int n0 = __builtin_amdgcn_readfirstlane(wave) * 32;
  if (n0 >= NB_NITEMS) return;
  int lr = ln & 15, lg = ln >> 4;

  short8 bfr[2][4];
#pragma unroll
  for (int nf = 0; nf < 2; nf++) {
    const ushort* base = embB + (size_t)(n0 + nf * 16 + lr) * 128 + lg * 8;
#pragma unroll
    for (int kf = 0; kf < 4; kf++) bfr[nf][kf] = *(const short8*)(base + kf * 32);
  }

  f32x4 acc[16][2] = {};
#pragma unroll
  for (int mg = 0; mg < 4; mg++) {
    short8 afr[4][4];
#pragma unroll
    for (int mf = 0; mf < 4; mf++) {
      const ushort* ab = GHT_bf + (size_t)((mg * 4 + mf) * 16 + lr) * 128 + lg * 8;
#pragma unroll
      for (int kf = 0; kf < 4; kf++) afr[mf][kf] = *(const short8*)(ab + kf * 32);
    }
#pragma unroll
    for (int mf = 0; mf < 4; mf++)
#pragma unroll
      for (int nf = 0; nf < 2; nf++)
#pragma unroll
        for (int kf = 0; kf < 4; kf++)
          acc[mg * 4 + mf][nf] = __builtin_amdgcn_mfma_f32_16x16x32_bf16(
              afr[mf][kf], bfr[nf][kf], acc[mg * 4 + mf][nf], 0, 0, 0);
  }

#pragma unroll
  for (int mf = 0; mf < 16; mf++)
#pragma unroll
    for (int nf = 0; nf < 2; nf++) {
      int n = n0 + nf * 16 + lr;
#pragma unroll
      for (int r = 0; r < 4; r++) {
        int m = mf * 16 + lg * 4 + r;
        out[(size_t)m * NB_NITEMS + n] = fmaxf(acc[mf][nf][r], 0.f);
      }
    }
}

extern "C" void kernel_launch(void* const* d_in, const int* in_sizes, int n_in,
                              void* d_out, int out_size, void* d_ws, size_t ws_size,
                              hipStream_t stream) {
  const int* h_iids = (const int*)d_in[0];
  const int* adj_e = (const int*)d_in[2];
  const int* adj_r = (const int*)d_in[3];
  const float* item_emb = (const float*)d_in[4];
  const float* rel_emb = (const float*)d_in[5];
  const float* Wa = (const float*)d_in[6];
  const float* Wt = (const float*)d_in[8];
  const float* bt = (const float*)d_in[9];
  const float* Wih = (const float*)d_in[10];
  const float* Whh = (const float*)d_in[11];
  const float* bih = (const float*)d_in[12];
  const float* bhh = (const float*)d_in[13];
  const float* W1 = (const float*)d_in[14];
  const float* b1 = (const float*)d_in[15];
  const float* W2 = (const float*)d_in[16];
  const float* b2 = (const float*)d_in[17];
  const float* W3 = (const float*)d_in[18];
  const float* Wtr = (const float*)d_in[19];
  const float* btr = (const float*)d_in[20];
  float* out = (float*)d_out;

  // ws layout (bytes), all 16B-aligned. ~85.3 MB total.
  char* w = (char*)d_ws;
  uint* EMB_BF = (uint*)w;                    w += 25600000;  // 100000x128 bf16
  uint* REL_BF = (uint*)w;                    w += 51200;     // 200x128 bf16
  ushort* WtT_bf = (ushort*)w;                w += 32768;     // [128][128]
  ushort* WihT_bf = (ushort*)w;               w += 98304;     // [384][128]
  ushort* WhhT_bf = (ushort*)w;               w += 98304;     // [384][128]
  ushort* W2T_bf = (ushort*)w;                w += 32768;     // [128][128]
  uint* NEIB_bf = (uint*)w;                   w += 26214400;  // 102400x128 bf16
  uint* X1_bf = (uint*)w;                     w += 3276800;   // 12800x128 bf16
  uint* SEQ_bf = (uint*)w;                    w += 3276800;   // 12800x128 bf16
  float* GI = (float*)w;                      w += 19660800;  // 12800x384 fp32
  float* GOUT = (float*)w;                    w += 6553600;   // 12800x128 fp32
  float* LOCAL = (float*)w;                   w += 131072;
  float* Q1 = (float*)w;                      w += 131072;
  float* AL = (float*)w;                      w += 51200;
  ushort* GHT_bf = (ushort*)w;                w += 65536;

  // Aliases into dead regions (recomputed every launch -> replay-safe):
  uint* X0_bf = (uint*)d_out;                 // hop0 out; logits overwrites d_out
  ushort* GOUT_bf = (ushort*)X1_bf;           // X1_bf dead after SEQ GEMM
  float* Q2 = (float*)NEIB_bf;                // NEIB_bf dead after hop1

  // ---- prep casts ----
  castf_kernel<<<6250, 256, 0, stream>>>(item_emb, EMB_BF, 1600000);
  castf_kernel<<<13, 256, 0, stream>>>(rel_emb, REL_BF, 3200);
  castT_kernel<128, 128><<<64, 256, 0, stream>>>(Wt, WtT_bf);
  castT_kernel<128, 384><<<192, 256, 0, stream>>>(Wih, WihT_bf);
  castT_kernel<128, 384><<<192, 256, 0, stream>>>(Whh, WhhT_bf);
  castT_kernel<128, 128><<<64, 256, 0, stream>>>(W2, W2T_bf);

  // ---- KG hops ----
  hop_kernel<0><<<25600, 256, 0, stream>>>(h_iids, adj_e, adj_r, EMB_BF, REL_BF,
                                           nullptr, Wa, X0_bf, 102400);
  linm_kernel<128, 32, true><<<800, 256, 0, stream>>>(
      (const ushort*)X0_bf, WtT_bf, bt, nullptr, (ushort*)NEIB_bf, 102400);
  hop_kernel<1><<<3200, 256, 0, stream>>>(h_iids, adj_e, adj_r, EMB_BF, REL_BF,
                                          NEIB_bf, Wa, X1_bf, 12800);
  linm_kernel<128, 32, true><<<100, 256, 0, stream>>>(
      (const ushort*)X1_bf, WtT_bf, bt, nullptr, (ushort*)SEQ_bf, 12800);
  linm_kernel<384, 16, false><<<200, 256, 0, stream>>>(
      (const ushort*)SEQ_bf, WihT_bf, bih, GI, nullptr, 12800);

  // ---- GRU + pooling ----
  gru_mfma_kernel<<<16, 512, 0, stream>>>(GI, WhhT_bf, bhh, GOUT, GOUT_bf);
  pool_a_kernel<<<256, 128, 0, stream>>>(h_iids, GOUT, W1, b1, LOCAL, Q1);
  linm_kernel<128, 32, false><<<100, 256, 0, stream>>>(
      GOUT_bf, W2T_bf, b2, Q2, nullptr, 12800);
  pool_b2_kernel<<<3200, 256, 0, stream>>>(Q2, Q1, W3, AL);
  pool_c_kernel<<<256, 128, 0, stream>>>(GOUT, AL, LOCAL, Wtr, btr, GHT_bf);

  // ---- logits ----
  logits_mfma_kernel<<<782, 256, 0, stream>>>(GHT_bf, (const ushort*)EMB_BF, out);
}

// Round 8
// 292.529 us; speedup vs baseline: 1.0397x; 1.0146x over previous
//
#include <hip/hip_runtime.h>
#include <hip/hip_bf16.h>
#include <math.h>

#define NB_B 256
#define NB_S 50
#define NB_NB 8
#define NB_D 128
#define NB_NITEMS 100000

typedef __attribute__((ext_vector_type(8))) short short8;   // 8 x bf16 (4 VGPR)
typedef __attribute__((ext_vector_type(4))) float f32x4;    // MFMA acc
typedef unsigned int uint;
typedef unsigned short ushort;

__device__ __forceinline__ float wave_sum(float t) {
#pragma unroll
  for (int off = 32; off; off >>= 1) t += __shfl_xor(t, off);
  return t;
}

__device__ __forceinline__ float sigf(float x) { return 1.f / (1.f + __expf(-x)); }

// fp32 -> bf16 round-to-nearest-even
__device__ __forceinline__ ushort f2bf(float f) {
  union { float f; uint u; } v;
  v.f = f;
  return (ushort)((v.u + 0x7fffu + ((v.u >> 16) & 1u)) >> 16);
}
__device__ __forceinline__ uint packbf(float a, float b) {
  return (uint)f2bf(a) | ((uint)f2bf(b) << 16);
}
__device__ __forceinline__ float bflo(uint u) {
  union { uint u; float f; } v; v.u = u << 16; return v.f;
}
__device__ __forceinline__ float bfhi(uint u) {
  union { uint u; float f; } v; v.u = u & 0xffff0000u; return v.f;
}

// ---------------- elementwise fp32 -> packed bf16 (8 floats / thread) ----------------
__global__ __launch_bounds__(256) void castf_kernel(const float* __restrict__ src,
                                                    uint* __restrict__ dst, int n8) {
  int i = blockIdx.x * 256 + threadIdx.x;
  if (i >= n8) return;
  float4 a = ((const float4*)src)[2 * i];
  float4 b = ((const float4*)src)[2 * i + 1];
  uint4 o;
  o.x = packbf(a.x, a.y);
  o.y = packbf(a.z, a.w);
  o.z = packbf(b.x, b.y);
  o.w = packbf(b.z, b.w);
  ((uint4*)dst)[i] = o;
}

// ---------------- W[K][CO] -> WT bf16 [CO][K] ----------------
template <int K, int CO>
__global__ __launch_bounds__(256) void castT_kernel(const float* __restrict__ W,
                                                    ushort* __restrict__ WT) {
  int idx = blockIdx.x * 256 + threadIdx.x;
  if (idx >= K * CO) return;
  int n = idx / K, k = idx % K;
  WT[idx] = f2bf(W[(size_t)k * CO + n]);
}

// ---------------- hop aggregation (bf16 tables, packed pairs) ----------------
template <int LEVEL>
__global__ __launch_bounds__(256) void hop_kernel(
    const int* __restrict__ h_iids, const int* __restrict__ adj_e,
    const int* __restrict__ adj_r, const uint* __restrict__ embB,
    const uint* __restrict__ relB, const uint* __restrict__ neibB,
    const float* __restrict__ Wa, uint* __restrict__ Xout, int npairs) {
  int p = (int)((blockIdx.x * blockDim.x + threadIdx.x) >> 6);
  p = __builtin_amdgcn_readfirstlane(p);
  int ln = threadIdx.x & 63;
  if (p >= npairs) return;

  int e_self;
  if (LEVEL == 0) {
    int b = p / (NB_S * NB_NB);
    int m = p % (NB_S * NB_NB);
    int s = m >> 3, j = m & 7;
    int h = h_iids[b * NB_S + s];
    e_self = adj_e[h * NB_NB + j];
  } else {
    e_self = h_iids[p];
  }

  float wa0 = Wa[2 * ln], wa1 = Wa[2 * ln + 1];
  uint us = embB[(size_t)e_self * 64 + ln];
  float s0 = bflo(us), s1 = bfhi(us);

  float nb0[NB_NB], nb1[NB_NB], att[NB_NB];
#pragma unroll
  for (int k = 0; k < NB_NB; k++) {
    int r = adj_r[e_self * NB_NB + k];
    uint un;
    if (LEVEL == 0) {
      int e2 = adj_e[e_self * NB_NB + k];
      un = embB[(size_t)e2 * 64 + ln];
    } else {
      un = neibB[((size_t)p * NB_NB + k) * 64 + ln];
    }
    uint ur = relB[r * 64 + ln];
    nb0[k] = bflo(un);
    nb1[k] = bfhi(un);
    float t = s0 * bflo(ur) * nb0[k] * wa0 + s1 * bfhi(ur) * nb1[k] * wa1;
    att[k] = wave_sum(t);
  }
  // |att| <= ~0.04 -> exp safe without max-subtraction (softmax-invariant)
  float den = 0.f, ex[NB_NB];
#pragma unroll
  for (int k = 0; k < NB_NB; k++) { ex[k] = __expf(att[k]); den += ex[k]; }
  float inv = 1.f / den;
  float x0 = s0, x1 = s1;
#pragma unroll
  for (int k = 0; k < NB_NB; k++) {
    float a = ex[k] * inv;
    x0 += a * nb0[k];
    x1 += a * nb1[k];
  }
  Xout[(size_t)p * 64 + ln] = packbf(x0, x1);
}

// ---------------- Y[N,CO] = Xbf[N,128] @ WT_bf^T + bias  (MFMA, no LDS) ----------------
template <int CO, int MPW, bool OUT_BF>
__global__ __launch_bounds__(256) void linm_kernel(
    const ushort* __restrict__ Xbf, const ushort* __restrict__ WT,
    const float* __restrict__ bias, float* __restrict__ Yf,
    ushort* __restrict__ Yb, int nrows) {
  constexpr int NF = CO / 16;
  constexpr int MF = MPW / 16;
  int wave = (int)(blockIdx.x * 4 + (threadIdx.x >> 6));
  int ln = threadIdx.x & 63;
  int m0 = __builtin_amdgcn_readfirstlane(wave) * MPW;
  if (m0 >= nrows) return;
  int lr = ln & 15, lg = ln >> 4;

  short8 afr[MF][4];
#pragma unroll
  for (int mf = 0; mf < MF; mf++) {
    const ushort* ab = Xbf + (size_t)(m0 + mf * 16 + lr) * 128 + lg * 8;
#pragma unroll
    for (int kf = 0; kf < 4; kf++) afr[mf][kf] = *(const short8*)(ab + kf * 32);
  }
  f32x4 acc[MF][NF] = {};
#pragma unroll
  for (int nf = 0; nf < NF; nf++) {
    const ushort* bb = WT + (size_t)(nf * 16 + lr) * 128 + lg * 8;
#pragma unroll
    for (int kf = 0; kf < 4; kf++) {
      short8 b = *(const short8*)(bb + kf * 32);
#pragma unroll
      for (int mf = 0; mf < MF; mf++)
        acc[mf][nf] = __builtin_amdgcn_mfma_f32_16x16x32_bf16(afr[mf][kf], b,
                                                              acc[mf][nf], 0, 0, 0);
    }
  }
#pragma unroll
  for (int mf = 0; mf < MF; mf++)
#pragma unroll
    for (int nf = 0; nf < NF; nf++) {
      int n = nf * 16 + lr;
      float bv = bias[n];
#pragma unroll
      for (int r = 0; r < 4; r++) {
        int m = m0 + mf * 16 + lg * 4 + r;
        float val = acc[mf][nf][r] + bv;
        if (OUT_BF)
          Yb[(size_t)m * CO + n] = f2bf(val);
        else
          Yf[(size_t)m * CO + n] = val;
      }
    }
}

// ---------------- GRU: lane-local gates, 1 barrier/step ----------------
// 16 blocks x 512 threads; block owns 16 batch rows.
// Wave w owns dim-cols j in [16w,16w+16) of ALL THREE gate groups
// (n = j, 128+j, 256+j). By the C/D layout (col=lane&15, row=(lane>>4)*4+r),
// lane (lr,lg) gets GH_r/GH_z/GH_n for (batch=lg*4+r, dim=16w+lr) in
// REGISTERS -- gates, identity path, and OUT stores are lane-local.
// h_bf double-buffered (hA/hB) -> single barrier per step.
// NOTE: n-gate is tanh(inn + r*(gh_n + bhh_n)) -- bhh_n INSIDE the r* term.
__global__ __launch_bounds__(512) void gru_mfma_kernel(
    const float* __restrict__ GI, const ushort* __restrict__ WhhT_bf,
    const float* __restrict__ bhh, float* __restrict__ OUT,
    ushort* __restrict__ OUTB) {
  const int b0 = blockIdx.x * 16;
  const int tid = threadIdx.x;
  const int w = tid >> 6, ln = tid & 63;
  const int lr = ln & 15, lg = ln >> 4;
  const int j = w * 16 + lr;  // this lane's dim-column

  __shared__ ushort hA[16 * 128];  // XOR-swizzled bf16 h, double-buffered
  __shared__ ushort hB[16 * 128];

  // B-frags: gate g (0=r,1=z,2=n), cols n = g*128 + j
  short8 bfr[3][4];
#pragma unroll
  for (int g = 0; g < 3; g++) {
    const ushort* bb = WhhT_bf + (size_t)(g * 128 + j) * 128 + lg * 8;
#pragma unroll
    for (int kf = 0; kf < 4; kf++) bfr[g][kf] = *(const short8*)(bb + kf * 32);
  }

  float bh[3];
#pragma unroll
  for (int g = 0; g < 3; g++) bh[g] = bhh[g * 128 + j];

  float h_reg[4] = {0.f, 0.f, 0.f, 0.f};  // fp32 identity path, lane-local

  {  // zero hA (t=0 A operand)
    uint* hz = (uint*)hA;
#pragma unroll
    for (int i = tid; i < 1024; i += 512) hz[i] = 0;
  }
  __syncthreads();

  // GI prefetch for t=0: gir[r][g] = GI[b0+lg*4+r][t][g*128+j]
  float girA[4][3], girB[4][3];
#pragma unroll
  for (int r = 0; r < 4; r++) {
    const float* g = GI + ((size_t)(b0 + lg * 4 + r) * NB_S + 0) * 384 + j;
    girA[r][0] = g[0]; girA[r][1] = g[128]; girA[r][2] = g[256];
  }

  auto STEP = [&](int t, ushort* hRead, ushort* hWrite, float (&cur)[4][3],
                  float (&nxt)[4][3]) {
    // A-frags from swizzled hRead
    short8 afr[4];
#pragma unroll
    for (int kf = 0; kf < 4; kf++) {
      int byte = (lr * 256 + kf * 64 + lg * 16) ^ ((lr & 7) << 4);
      afr[kf] = *(const short8*)((const char*)hRead + byte);
    }
    // prefetch GI for t+1 (in flight across MFMA+gates+barrier)
    if (t + 1 < NB_S) {
#pragma unroll
      for (int r = 0; r < 4; r++) {
        const float* g = GI + ((size_t)(b0 + lg * 4 + r) * NB_S + (t + 1)) * 384 + j;
        nxt[r][0] = g[0]; nxt[r][1] = g[128]; nxt[r][2] = g[256];
      }
    }
    f32x4 acc[3] = {};
#pragma unroll
    for (int g = 0; g < 3; g++)
#pragma unroll
      for (int kf = 0; kf < 4; kf++)
        acc[g] = __builtin_amdgcn_mfma_f32_16x16x32_bf16(afr[kf], bfr[g][kf],
                                                         acc[g], 0, 0, 0);
    // gates: all operands lane-local
#pragma unroll
    for (int r = 0; r < 4; r++) {
      int b = lg * 4 + r;
      float rg = sigf(cur[r][0] + bh[0] + acc[0][r]);
      float zg = sigf(cur[r][1] + bh[1] + acc[1][r]);
      float x = cur[r][2] + rg * (bh[2] + acc[2][r]);  // bias INSIDE r*
      float e2 = __expf(2.f * x);
      float n = 1.f - 2.f / (e2 + 1.f);  // tanh(x)
      float h2 = (1.f - zg) * n + zg * h_reg[r];
      h_reg[r] = h2;
      size_t o = ((size_t)(b0 + b) * NB_S + t) * 128 + j;
      OUT[o] = h2;
      ushort hb = f2bf(h2);
      OUTB[o] = hb;
      int byte = (b * 256 + j * 2) ^ ((b & 7) << 4);
      *(ushort*)((char*)hWrite + byte) = hb;
    }
    asm volatile("s_waitcnt lgkmcnt(0)" ::: "memory");
    __builtin_amdgcn_s_barrier();  // hWrite visible; global loads stay in flight
  };

  for (int t2 = 0; t2 < NB_S; t2 += 2) {
    STEP(t2, hA, hB, girA, girB);
    STEP(t2 + 1, hB, hA, girB, girA);
  }
}

// ---------------- pooling ----------------
__global__ __launch_bounds__(128) void pool_a_kernel(
    const int* __restrict__ h_iids, const float* __restrict__ OUT,
    const float* __restrict__ W1, const float* __restrict__ b1,
    float* __restrict__ LOCAL, float* __restrict__ Q1) {
  int b = blockIdx.x, c = threadIdx.x;
  int cnt = 0;
  for (int s = 0; s < NB_S; s++) cnt += (h_iids[b * NB_S + s] != 0);
  int li = min(max(cnt - 1, 0), NB_S - 1);
  __shared__ float lh[128];
  float lv = OUT[((size_t)b * NB_S + li) * 128 + c];
  lh[c] = lv;
  LOCAL[b * 128 + c] = lv;
  __syncthreads();
  float acc = b1[c];
  for (int d = 0; d < 128; d++) acc += lh[d] * W1[(size_t)d * 128 + c];
  Q1[b * 128 + c] = acc;
}

// AL[p] = sum_n sigmoid(Q1[b][n] + Q2[p][n]) * W3[n]
__global__ __launch_bounds__(256) void pool_b2_kernel(
    const float* __restrict__ Q2, const float* __restrict__ Q1,
    const float* __restrict__ W3, float* __restrict__ AL) {
  int p = (int)((blockIdx.x * blockDim.x + threadIdx.x) >> 6);
  p = __builtin_amdgcn_readfirstlane(p);
  int ln = threadIdx.x & 63;
  if (p >= NB_B * NB_S) return;
  int b = p / NB_S;
  float t = sigf(Q1[b * 128 + ln] + Q2[(size_t)p * 128 + ln]) * W3[ln] +
            sigf(Q1[b * 128 + 64 + ln] + Q2[(size_t)p * 128 + 64 + ln]) * W3[64 + ln];
  t = wave_sum(t);
  if (ln == 0) AL[p] = t;
}

__global__ __launch_bounds__(128) void pool_c_kernel(
    const float* __restrict__ OUT, const float* __restrict__ AL,
    const float* __restrict__ LOCAL, const float* __restrict__ Wtr,
    const float* __restrict__ btr, ushort* __restrict__ GHT_bf) {
  int b = blockIdx.x, d = threadIdx.x;
  float g = 0.f;
  for (int s = 0; s < NB_S; s++)
    g += AL[b * NB_S + s] * OUT[((size_t)b * NB_S + s) * 128 + d];
  __shared__ float cat[256];
  cat[d] = LOCAL[b * 128 + d];
  cat[128 + d] = g;
  __syncthreads();
  float acc = btr[d];
  for (int dd = 0; dd < 256; dd++) acc += cat[dd] * Wtr[(size_t)dd * 128 + d];
  GHT_bf[b * 128 + d] = f2bf(acc);
}

// ---------------- logits = relu(GHT_bf @ EMB_BF^T) via MFMA ----------------
__global__ __launch_bounds__(256) void logits_mfma_kernel(
    const ushort* __restrict__ GHT_bf, const ushort* __restrict__ embB,
    float* __restrict__ out) {
  int wave = (int)(blockIdx.x * 4 + (threadIdx.x >> 6));
  int ln = threadIdx.x & 63;
  int n0 = __builtin_amdgcn_readfirstlane(wave) * 32;
  if (n0 >= NB_NITEMS) return;
  int lr = ln & 15, lg = ln >> 4;

  short8 bfr[2][4];
#pragma unroll
  for (int nf = 0; nf < 2; nf++) {
    const ushort* base = embB + (size_t)(n0 + nf * 16 + lr) * 128 + lg * 8;
#pragma unroll
    for (int kf = 0; kf < 4; kf++) bfr[nf][kf] = *(const short8*)(base + kf * 32);
  }

  f32x4 acc[16][2] = {};
#pragma unroll
  for (int mg = 0; mg < 4; mg++) {
    short8 afr[4][4];
#pragma unroll
    for (int mf = 0; mf < 4; mf++) {
      const ushort* ab = GHT_bf + (size_t)((mg * 4 + mf) * 16 + lr) * 128 + lg * 8;
#pragma unroll
      for (int kf = 0; kf < 4; kf++) afr[mf][kf] = *(const short8*)(ab + kf * 32);
    }
#pragma unroll
    for (int mf = 0; mf < 4; mf++)
#pragma unroll
      for (int nf = 0; nf < 2; nf++)
#pragma unroll
        for (int kf = 0; kf < 4; kf++)
          acc[mg * 4 + mf][nf] = __builtin_amdgcn_mfma_f32_16x16x32_bf16(
              afr[mf][kf], bfr[nf][kf], acc[mg * 4 + mf][nf], 0, 0, 0);
  }

#pragma unroll
  for (int mf = 0; mf < 16; mf++)
#pragma unroll
    for (int nf = 0; nf < 2; nf++) {
      int n = n0 + nf * 16 + lr;
#pragma unroll
      for (int r = 0; r < 4; r++) {
        int m = mf * 16 + lg * 4 + r;
        out[(size_t)m * NB_NITEMS + n] = fmaxf(acc[mf][nf][r], 0.f);
      }
    }
}

extern "C" void kernel_launch(void* const* d_in, const int* in_sizes, int n_in,
                              void* d_out, int out_size, void* d_ws, size_t ws_size,
                              hipStream_t stream) {
  const int* h_iids = (const int*)d_in[0];
  const int* adj_e = (const int*)d_in[2];
  const int* adj_r = (const int*)d_in[3];
  const float* item_emb = (const float*)d_in[4];
  const float* rel_emb = (const float*)d_in[5];
  const float* Wa = (const float*)d_in[6];
  const float* Wt = (const float*)d_in[8];
  const float* bt = (const float*)d_in[9];
  const float* Wih = (const float*)d_in[10];
  const float* Whh = (const float*)d_in[11];
  const float* bih = (const float*)d_in[12];
  const float* bhh = (const float*)d_in[13];
  const float* W1 = (const float*)d_in[14];
  const float* b1 = (const float*)d_in[15];
  const float* W2 = (const float*)d_in[16];
  const float* b2 = (const float*)d_in[17];
  const float* W3 = (const float*)d_in[18];
  const float* Wtr = (const float*)d_in[19];
  const float* btr = (const float*)d_in[20];
  float* out = (float*)d_out;

  // ws layout (bytes), all 16B-aligned. ~85.3 MB total.
  char* w = (char*)d_ws;
  uint* EMB_BF = (uint*)w;                    w += 25600000;  // 100000x128 bf16
  uint* REL_BF = (uint*)w;                    w += 51200;     // 200x128 bf16
  ushort* WtT_bf = (ushort*)w;                w += 32768;     // [128][128]
  ushort* WihT_bf = (ushort*)w;               w += 98304;     // [384][128]
  ushort* WhhT_bf = (ushort*)w;               w += 98304;     // [384][128]
  ushort* W2T_bf = (ushort*)w;                w += 32768;     // [128][128]
  uint* NEIB_bf = (uint*)w;                   w += 26214400;  // 102400x128 bf16
  uint* X1_bf = (uint*)w;                     w += 3276800;   // 12800x128 bf16
  uint* SEQ_bf = (uint*)w;                    w += 3276800;   // 12800x128 bf16
  float* GI = (float*)w;                      w += 19660800;  // 12800x384 fp32
  float* GOUT = (float*)w;                    w += 6553600;   // 12800x128 fp32
  float* LOCAL = (float*)w;                   w += 131072;
  float* Q1 = (float*)w;                      w += 131072;
  float* AL = (float*)w;                      w += 51200;
  ushort* GHT_bf = (ushort*)w;                w += 65536;

  // Aliases into dead regions (recomputed every launch -> replay-safe):
  uint* X0_bf = (uint*)d_out;                 // hop0 out; logits overwrites d_out
  ushort* GOUT_bf = (ushort*)X1_bf;           // X1_bf dead after SEQ GEMM
  float* Q2 = (float*)NEIB_bf;                // NEIB_bf dead after hop1

  // ---- prep casts ----
  castf_kernel<<<6250, 256, 0, stream>>>(item_emb, EMB_BF, 1600000);
  castf_kernel<<<13, 256, 0, stream>>>(rel_emb, REL_BF, 3200);
  castT_kernel<128, 128><<<64, 256, 0, stream>>>(Wt, WtT_bf);
  castT_kernel<128, 384><<<192, 256, 0, stream>>>(Wih, WihT_bf);
  castT_kernel<128, 384><<<192, 256, 0, stream>>>(Whh, WhhT_bf);
  castT_kernel<128, 128><<<64, 256, 0, stream>>>(W2, W2T_bf);

  // ---- KG hops ----
  hop_kernel<0><<<25600, 256, 0, stream>>>(h_iids, adj_e, adj_r, EMB_BF, REL_BF,
                                           nullptr, Wa, X0_bf, 102400);
  linm_kernel<128, 32, true><<<800, 256, 0, stream>>>(
      (const ushort*)X0_bf, WtT_bf, bt, nullptr, (ushort*)NEIB_bf, 102400);
  hop_kernel<1><<<3200, 256, 0, stream>>>(h_iids, adj_e, adj_r, EMB_BF, REL_BF,
                                          NEIB_bf, Wa, X1_bf, 12800);
  linm_kernel<128, 32, true><<<100, 256, 0, stream>>>(
      (const ushort*)X1_bf, WtT_bf, bt, nullptr, (ushort*)SEQ_bf, 12800);
  linm_kernel<384, 16, false><<<200, 256, 0, stream>>>(
      (const ushort*)SEQ_bf, WihT_bf, bih, GI, nullptr, 12800);

  // ---- GRU + pooling ----
  gru_mfma_kernel<<<16, 512, 0, stream>>>(GI, WhhT_bf, bhh, GOUT, GOUT_bf);
  pool_a_kernel<<<256, 128, 0, stream>>>(h_iids, GOUT, W1, b1, LOCAL, Q1);
  linm_kernel<128, 32, false><<<100, 256, 0, stream>>>(
      GOUT_bf, W2T_bf, b2, Q2, nullptr, 12800);
  pool_b2_kernel<<<3200, 256, 0, stream>>>(Q2, Q1, W3, AL);
  pool_c_kernel<<<256, 128, 0, stream>>>(GOUT, AL, LOCAL, Wtr, btr, GHT_bf);

  // ---- logits ----
  logits_mfma_kernel<<<782, 256, 0, stream>>>(GHT_bf, (const ushort*)EMB_BF, out);
}

// Round 9
// 286.009 us; speedup vs baseline: 1.0634x; 1.0228x over previous
//
#include <hip/hip_runtime.h>
#include <hip/hip_bf16.h>
#include <math.h>

#define NB_B 256
#define NB_S 50
#define NB_NB 8
#define NB_D 128
#define NB_NITEMS 100000

typedef __attribute__((ext_vector_type(8))) short short8;   // 8 x bf16 (4 VGPR)
typedef __attribute__((ext_vector_type(4))) float f32x4;    // MFMA acc
typedef unsigned int uint;
typedef unsigned short ushort;

__device__ __forceinline__ float wave_sum(float t) {
#pragma unroll
  for (int off = 32; off; off >>= 1) t += __shfl_xor(t, off);
  return t;
}

__device__ __forceinline__ float sigf(float x) { return 1.f / (1.f + __expf(-x)); }

// fp32 -> bf16 round-to-nearest-even
__device__ __forceinline__ ushort f2bf(float f) {
  union { float f; uint u; } v;
  v.f = f;
  return (ushort)((v.u + 0x7fffu + ((v.u >> 16) & 1u)) >> 16);
}
__device__ __forceinline__ uint packbf(float a, float b) {
  return (uint)f2bf(a) | ((uint)f2bf(b) << 16);
}
__device__ __forceinline__ float bflo(uint u) {
  union { uint u; float f; } v; v.u = u << 16; return v.f;
}
__device__ __forceinline__ float bfhi(uint u) {
  union { uint u; float f; } v; v.u = u & 0xffff0000u; return v.f;
}

// ---------------- elementwise fp32 -> packed bf16 (8 floats / thread) ----------------
__global__ __launch_bounds__(256) void castf_kernel(const float* __restrict__ src,
                                                    uint* __restrict__ dst, int n8) {
  int i = blockIdx.x * 256 + threadIdx.x;
  if (i >= n8) return;
  float4 a = ((const float4*)src)[2 * i];
  float4 b = ((const float4*)src)[2 * i + 1];
  uint4 o;
  o.x = packbf(a.x, a.y);
  o.y = packbf(a.z, a.w);
  o.z = packbf(b.x, b.y);
  o.w = packbf(b.z, b.w);
  ((uint4*)dst)[i] = o;
}

// ---------------- W[K][CO] -> WT bf16 [CO][K] ----------------
template <int K, int CO>
__global__ __launch_bounds__(256) void castT_kernel(const float* __restrict__ W,
                                                    ushort* __restrict__ WT) {
  int idx = blockIdx.x * 256 + threadIdx.x;
  if (idx >= K * CO) return;
  int n = idx / K, k = idx % K;
  WT[idx] = f2bf(W[(size_t)k * CO + n]);
}

// ---------------- hop aggregation (bf16 tables, packed pairs) ----------------
template <int LEVEL>
__global__ __launch_bounds__(256) void hop_kernel(
    const int* __restrict__ h_iids, const int* __restrict__ adj_e,
    const int* __restrict__ adj_r, const uint* __restrict__ embB,
    const uint* __restrict__ relB, const uint* __restrict__ neibB,
    const float* __restrict__ Wa, uint* __restrict__ Xout, int npairs) {
  int p = (int)((blockIdx.x * blockDim.x + threadIdx.x) >> 6);
  p = __builtin_amdgcn_readfirstlane(p);
  int ln = threadIdx.x & 63;
  if (p >= npairs) return;

  int e_self;
  if (LEVEL == 0) {
    int b = p / (NB_S * NB_NB);
    int m = p % (NB_S * NB_NB);
    int s = m >> 3, j = m & 7;
    int h = h_iids[b * NB_S + s];
    e_self = adj_e[h * NB_NB + j];
  } else {
    e_self = h_iids[p];
  }

  float wa0 = Wa[2 * ln], wa1 = Wa[2 * ln + 1];
  uint us = embB[(size_t)e_self * 64 + ln];
  float s0 = bflo(us), s1 = bfhi(us);

  float nb0[NB_NB], nb1[NB_NB], att[NB_NB];
#pragma unroll
  for (int k = 0; k < NB_NB; k++) {
    int r = adj_r[e_self * NB_NB + k];
    uint un;
    if (LEVEL == 0) {
      int e2 = adj_e[e_self * NB_NB + k];
      un = embB[(size_t)e2 * 64 + ln];
    } else {
      un = neibB[((size_t)p * NB_NB + k) * 64 + ln];
    }
    uint ur = relB[r * 64 + ln];
    nb0[k] = bflo(un);
    nb1[k] = bfhi(un);
    float t = s0 * bflo(ur) * nb0[k] * wa0 + s1 * bfhi(ur) * nb1[k] * wa1;
    att[k] = wave_sum(t);
  }
  // |att| <= ~0.04 -> exp safe without max-subtraction (softmax-invariant)
  float den = 0.f, ex[NB_NB];
#pragma unroll
  for (int k = 0; k < NB_NB; k++) { ex[k] = __expf(att[k]); den += ex[k]; }
  float inv = 1.f / den;
  float x0 = s0, x1 = s1;
#pragma unroll
  for (int k = 0; k < NB_NB; k++) {
    float a = ex[k] * inv;
    x0 += a * nb0[k];
    x1 += a * nb1[k];
  }
  Xout[(size_t)p * 64 + ln] = packbf(x0, x1);
}

// ---------------- Y[N,CO] = Xbf[N,128] @ WT_bf^T + bias  (MFMA, no LDS) ----------------
template <int CO, int MPW, bool OUT_BF>
__global__ __launch_bounds__(256) void linm_kernel(
    const ushort* __restrict__ Xbf, const ushort* __restrict__ WT,
    const float* __restrict__ bias, float* __restrict__ Yf,
    ushort* __restrict__ Yb, int nrows) {
  constexpr int NF = CO / 16;
  constexpr int MF = MPW / 16;
  int wave = (int)(blockIdx.x * 4 + (threadIdx.x >> 6));
  int ln = threadIdx.x & 63;
  int m0 = __builtin_amdgcn_readfirstlane(wave) * MPW;
  if (m0 >= nrows) return;
  int lr = ln & 15, lg = ln >> 4;

  short8 afr[MF][4];
#pragma unroll
  for (int mf = 0; mf < MF; mf++) {
    const ushort* ab = Xbf + (size_t)(m0 + mf * 16 + lr) * 128 + lg * 8;
#pragma unroll
    for (int kf = 0; kf < 4; kf++) afr[mf][kf] = *(const short8*)(ab + kf * 32);
  }
  f32x4 acc[MF][NF] = {};
#pragma unroll
  for (int nf = 0; nf < NF; nf++) {
    const ushort* bb = WT + (size_t)(nf * 16 + lr) * 128 + lg * 8;
#pragma unroll
    for (int kf = 0; kf < 4; kf++) {
      short8 b = *(const short8*)(bb + kf * 32);
#pragma unroll
      for (int mf = 0; mf < MF; mf++)
        acc[mf][nf] = __builtin_amdgcn_mfma_f32_16x16x32_bf16(afr[mf][kf], b,
                                                              acc[mf][nf], 0, 0, 0);
    }
  }
#pragma unroll
  for (int mf = 0; mf < MF; mf++)
#pragma unroll
    for (int nf = 0; nf < NF; nf++) {
      int n = nf * 16 + lr;
      float bv = bias[n];
#pragma unroll
      for (int r = 0; r < 4; r++) {
        int m = m0 + mf * 16 + lg * 4 + r;
        float val = acc[mf][nf][r] + bv;
        if (OUT_BF)
          Yb[(size_t)m * CO + n] = f2bf(val);
        else
          Yf[(size_t)m * CO + n] = val;
      }
    }
}

// ---------------- GRU: lane-local gates, depth-2 GI register pipeline ----------------
// 16 blocks x 512 threads; block owns 16 batch rows.
// Evidence (R4/R6/R7/R8 all ~75us regardless of step structure): the cost is
// exposed GLOBAL-load latency of the per-step scattered GI reads at <=1-step
// prefetch depth. Fix: 3 named register buffers (girA/B/C), loads for t+2
// issued at the TOP of step t, consumed at t+2 (~2 steps ~1200+cyc in flight).
// Barriers drain lgkmcnt only, so the loads stay in flight across them.
// NOTE: n-gate is tanh(inn + r*(gh_n + bhh_n)) -- bhh_n INSIDE the r* term.
__global__ __launch_bounds__(512) void gru_mfma_kernel(
    const float* __restrict__ GI, const ushort* __restrict__ WhhT_bf,
    const float* __restrict__ bhh, float* __restrict__ OUT,
    ushort* __restrict__ OUTB) {
  const int b0 = blockIdx.x * 16;
  const int tid = threadIdx.x;
  const int w = tid >> 6, ln = tid & 63;
  const int lr = ln & 15, lg = ln >> 4;
  const int j = w * 16 + lr;  // this lane's dim-column

  __shared__ ushort hA[16 * 128];  // XOR-swizzled bf16 h, double-buffered
  __shared__ ushort hB[16 * 128];

  // B-frags: gate g (0=r,1=z,2=n), cols n = g*128 + j
  short8 bfr[3][4];
#pragma unroll
  for (int g = 0; g < 3; g++) {
    const ushort* bb = WhhT_bf + (size_t)(g * 128 + j) * 128 + lg * 8;
#pragma unroll
    for (int kf = 0; kf < 4; kf++) bfr[g][kf] = *(const short8*)(bb + kf * 32);
  }

  float bh[3];
#pragma unroll
  for (int g = 0; g < 3; g++) bh[g] = bhh[g * 128 + j];

  float h_reg[4] = {0.f, 0.f, 0.f, 0.f};  // fp32 identity path, lane-local

  {  // zero hA (t=0 A operand)
    uint* hz = (uint*)hA;
#pragma unroll
    for (int i = tid; i < 1024; i += 512) hz[i] = 0;
  }
  __syncthreads();

  // GI register pipeline, depth 2: girX[r][g] = GI[b0+lg*4+r][t][g*128+j]
  float girA[4][3], girB[4][3], girC[4][3];
#pragma unroll
  for (int r = 0; r < 4; r++) {
    const float* g0 = GI + ((size_t)(b0 + lg * 4 + r) * NB_S + 0) * 384 + j;
    girA[r][0] = g0[0]; girA[r][1] = g0[128]; girA[r][2] = g0[256];
    const float* g1 = GI + ((size_t)(b0 + lg * 4 + r) * NB_S + 1) * 384 + j;
    girB[r][0] = g1[0]; girB[r][1] = g1[128]; girB[r][2] = g1[256];
  }

  auto STEP = [&](int t, ushort* hRead, ushort* hWrite, float (&cur)[4][3],
                  float (&pre2)[4][3]) {
    // issue GI loads for t+2 FIRST (consumed 2 steps from now)
    if (t + 2 < NB_S) {
#pragma unroll
      for (int r = 0; r < 4; r++) {
        const float* g = GI + ((size_t)(b0 + lg * 4 + r) * NB_S + (t + 2)) * 384 + j;
        pre2[r][0] = g[0]; pre2[r][1] = g[128]; pre2[r][2] = g[256];
      }
    }
    // A-frags from swizzled hRead
    short8 afr[4];
#pragma unroll
    for (int kf = 0; kf < 4; kf++) {
      int byte = (lr * 256 + kf * 64 + lg * 16) ^ ((lr & 7) << 4);
      afr[kf] = *(const short8*)((const char*)hRead + byte);
    }
    f32x4 acc[3] = {};
#pragma unroll
    for (int g = 0; g < 3; g++)
#pragma unroll
      for (int kf = 0; kf < 4; kf++)
        acc[g] = __builtin_amdgcn_mfma_f32_16x16x32_bf16(afr[kf], bfr[g][kf],
                                                         acc[g], 0, 0, 0);
    // gates: all operands lane-local
#pragma unroll
    for (int r = 0; r < 4; r++) {
      int b = lg * 4 + r;
      float rg = sigf(cur[r][0] + bh[0] + acc[0][r]);
      float zg = sigf(cur[r][1] + bh[1] + acc[1][r]);
      float x = cur[r][2] + rg * (bh[2] + acc[2][r]);  // bias INSIDE r*
      float e2 = __expf(2.f * x);
      float n = 1.f - 2.f / (e2 + 1.f);  // tanh(x)
      float h2 = (1.f - zg) * n + zg * h_reg[r];
      h_reg[r] = h2;
      size_t o = ((size_t)(b0 + b) * NB_S + t) * 128 + j;
      OUT[o] = h2;
      ushort hb = f2bf(h2);
      OUTB[o] = hb;
      int byte = (b * 256 + j * 2) ^ ((b & 7) << 4);
      *(ushort*)((char*)hWrite + byte) = hb;
    }
    asm volatile("s_waitcnt lgkmcnt(0)" ::: "memory");
    __builtin_amdgcn_s_barrier();  // hWrite visible; global loads stay in flight
  };

  // 48 steps in 16 groups of 3 (rotation A,B,C), then 2 peeled.
  for (int g3 = 0; g3 < 16; g3++) {
    int t = g3 * 3;
    STEP(t + 0, (t & 1) ? hB : hA, (t & 1) ? hA : hB, girA, girC);
    STEP(t + 1, (t & 1) ? hA : hB, (t & 1) ? hB : hA, girB, girA);
    STEP(t + 2, (t & 1) ? hB : hA, (t & 1) ? hA : hB, girC, girB);
  }
  // t=48 (even): read hA, write hB; t=49: read hB, write hA
  STEP(48, hA, hB, girA, girC);
  STEP(49, hB, hA, girB, girA);
}

// ---------------- pooling ----------------
__global__ __launch_bounds__(128) void pool_a_kernel(
    const int* __restrict__ h_iids, const float* __restrict__ OUT,
    const float* __restrict__ W1, const float* __restrict__ b1,
    float* __restrict__ LOCAL, float* __restrict__ Q1) {
  int b = blockIdx.x, c = threadIdx.x;
  int cnt = 0;
  for (int s = 0; s < NB_S; s++) cnt += (h_iids[b * NB_S + s] != 0);
  int li = min(max(cnt - 1, 0), NB_S - 1);
  __shared__ float lh[128];
  float lv = OUT[((size_t)b * NB_S + li) * 128 + c];
  lh[c] = lv;
  LOCAL[b * 128 + c] = lv;
  __syncthreads();
  float acc = b1[c];
  for (int d = 0; d < 128; d++) acc += lh[d] * W1[(size_t)d * 128 + c];
  Q1[b * 128 + c] = acc;
}

// AL[p] = sum_n sigmoid(Q1[b][n] + Q2[p][n]) * W3[n]
__global__ __launch_bounds__(256) void pool_b2_kernel(
    const float* __restrict__ Q2, const float* __restrict__ Q1,
    const float* __restrict__ W3, float* __restrict__ AL) {
  int p = (int)((blockIdx.x * blockDim.x + threadIdx.x) >> 6);
  p = __builtin_amdgcn_readfirstlane(p);
  int ln = threadIdx.x & 63;
  if (p >= NB_B * NB_S) return;
  int b = p / NB_S;
  float t = sigf(Q1[b * 128 + ln] + Q2[(size_t)p * 128 + ln]) * W3[ln] +
            sigf(Q1[b * 128 + 64 + ln] + Q2[(size_t)p * 128 + 64 + ln]) * W3[64 + ln];
  t = wave_sum(t);
  if (ln == 0) AL[p] = t;
}

__global__ __launch_bounds__(128) void pool_c_kernel(
    const float* __restrict__ OUT, const float* __restrict__ AL,
    const float* __restrict__ LOCAL, const float* __restrict__ Wtr,
    const float* __restrict__ btr, ushort* __restrict__ GHT_bf) {
  int b = blockIdx.x, d = threadIdx.x;
  float g = 0.f;
  for (int s = 0; s < NB_S; s++)
    g += AL[b * NB_S + s] * OUT[((size_t)b * NB_S + s) * 128 + d];
  __shared__ float cat[256];
  cat[d] = LOCAL[b * 128 + d];
  cat[128 + d] = g;
  __syncthreads();
  float acc = btr[d];
  for (int dd = 0; dd < 256; dd++) acc += cat[dd] * Wtr[(size_t)dd * 128 + d];
  GHT_bf[b * 128 + d] = f2bf(acc);
}

// ---------------- logits = relu(GHT_bf @ EMB_BF^T) via MFMA ----------------
__global__ __launch_bounds__(256) void logits_mfma_kernel(
    const ushort* __restrict__ GHT_bf, const ushort* __restrict__ embB,
    float* __restrict__ out) {
  int wave = (int)(blockIdx.x * 4 + (threadIdx.x >> 6));
  int ln = threadIdx.x & 63;
  int n0 = __builtin_amdgcn_readfirstlane(wave) * 32;
  if (n0 >= NB_NITEMS) return;
  int lr = ln & 15, lg = ln >> 4;

  short8 bfr[2][4];
#pragma unroll
  for (int nf = 0; nf < 2; nf++) {
    const ushort* base = embB + (size_t)(n0 + nf * 16 + lr) * 128 + lg * 8;
#pragma unroll
    for (int kf = 0; kf < 4; kf++) bfr[nf][kf] = *(const short8*)(base + kf * 32);
  }

  f32x4 acc[16][2] = {};
#pragma unroll
  for (int mg = 0; mg < 4; mg++) {
    short8 afr[4][4];
#pragma unroll
    for (int mf = 0; mf < 4; mf++) {
      const ushort* ab = GHT_bf + (size_t)((mg * 4 + mf) * 16 + lr) * 128 + lg * 8;
#pragma unroll
      for (int kf = 0; kf < 4; kf++) afr[mf][kf] = *(const short8*)(ab + kf * 32);
    }
#pragma unroll
    for (int mf = 0; mf < 4; mf++)
#pragma unroll
      for (int nf = 0; nf < 2; nf++)
#pragma unroll
        for (int kf = 0; kf < 4; kf++)
          acc[mg * 4 + mf][nf] = __builtin_amdgcn_mfma_f32_16x16x32_bf16(
              afr[mf][kf], bfr[nf][kf], acc[mg * 4 + mf][nf], 0, 0, 0);
  }

#pragma unroll
  for (int mf = 0; mf < 16; mf++)
#pragma unroll
    for (int nf = 0; nf < 2; nf++) {
      int n = n0 + nf * 16 + lr;
#pragma unroll
      for (int r = 0; r < 4; r++) {
        int m = mf * 16 + lg * 4 + r;
        out[(size_t)m * NB_NITEMS + n] = fmaxf(acc[mf][nf][r], 0.f);
      }
    }
}

extern "C" void kernel_launch(void* const* d_in, const int* in_sizes, int n_in,
                              void* d_out, int out_size, void* d_ws, size_t ws_size,
                              hipStream_t stream) {
  const int* h_iids = (const int*)d_in[0];
  const int* adj_e = (const int*)d_in[2];
  const int* adj_r = (const int*)d_in[3];
  const float* item_emb = (const float*)d_in[4];
  const float* rel_emb = (const float*)d_in[5];
  const float* Wa = (const float*)d_in[6];
  const float* Wt = (const float*)d_in[8];
  const float* bt = (const float*)d_in[9];
  const float* Wih = (const float*)d_in[10];
  const float* Whh = (const float*)d_in[11];
  const float* bih = (const float*)d_in[12];
  const float* bhh = (const float*)d_in[13];
  const float* W1 = (const float*)d_in[14];
  const float* b1 = (const float*)d_in[15];
  const float* W2 = (const float*)d_in[16];
  const float* b2 = (const float*)d_in[17];
  const float* W3 = (const float*)d_in[18];
  const float* Wtr = (const float*)d_in[19];
  const float* btr = (const float*)d_in[20];
  float* out = (float*)d_out;

  // ws layout (bytes), all 16B-aligned. ~85.3 MB total.
  char* w = (char*)d_ws;
  uint* EMB_BF = (uint*)w;                    w += 25600000;  // 100000x128 bf16
  uint* REL_BF = (uint*)w;                    w += 51200;     // 200x128 bf16
  ushort* WtT_bf = (ushort*)w;                w += 32768;     // [128][128]
  ushort* WihT_bf = (ushort*)w;               w += 98304;     // [384][128]
  ushort* WhhT_bf = (ushort*)w;               w += 98304;     // [384][128]
  ushort* W2T_bf = (ushort*)w;                w += 32768;     // [128][128]
  uint* NEIB_bf = (uint*)w;                   w += 26214400;  // 102400x128 bf16
  uint* X1_bf = (uint*)w;                     w += 3276800;   // 12800x128 bf16
  uint* SEQ_bf = (uint*)w;                    w += 3276800;   // 12800x128 bf16
  float* GI = (float*)w;                      w += 19660800;  // 12800x384 fp32
  float* GOUT = (float*)w;                    w += 6553600;   // 12800x128 fp32
  float* LOCAL = (float*)w;                   w += 131072;
  float* Q1 = (float*)w;                      w += 131072;
  float* AL = (float*)w;                      w += 51200;
  ushort* GHT_bf = (ushort*)w;                w += 65536;

  // Aliases into dead regions (recomputed every launch -> replay-safe):
  uint* X0_bf = (uint*)d_out;                 // hop0 out; logits overwrites d_out
  ushort* GOUT_bf = (ushort*)X1_bf;           // X1_bf dead after SEQ GEMM
  float* Q2 = (float*)NEIB_bf;                // NEIB_bf dead after hop1

  // ---- prep casts ----
  castf_kernel<<<6250, 256, 0, stream>>>(item_emb, EMB_BF, 1600000);
  castf_kernel<<<13, 256, 0, stream>>>(rel_emb, REL_BF, 3200);
  castT_kernel<128, 128><<<64, 256, 0, stream>>>(Wt, WtT_bf);
  castT_kernel<128, 384><<<192, 256, 0, stream>>>(Wih, WihT_bf);
  castT_kernel<128, 384><<<192, 256, 0, stream>>>(Whh, WhhT_bf);
  castT_kernel<128, 128><<<64, 256, 0, stream>>>(W2, W2T_bf);

  // ---- KG hops ----
  hop_kernel<0><<<25600, 256, 0, stream>>>(h_iids, adj_e, adj_r, EMB_BF, REL_BF,
                                           nullptr, Wa, X0_bf, 102400);
  linm_kernel<128, 32, true><<<800, 256, 0, stream>>>(
      (const ushort*)X0_bf, WtT_bf, bt, nullptr, (ushort*)NEIB_bf, 102400);
  hop_kernel<1><<<3200, 256, 0, stream>>>(h_iids, adj_e, adj_r, EMB_BF, REL_BF,
                                          NEIB_bf, Wa, X1_bf, 12800);
  linm_kernel<128, 32, true><<<100, 256, 0, stream>>>(
      (const ushort*)X1_bf, WtT_bf, bt, nullptr, (ushort*)SEQ_bf, 12800);
  linm_kernel<384, 16, false><<<200, 256, 0, stream>>>(
      (const ushort*)SEQ_bf, WihT_bf, bih, GI, nullptr, 12800);

  // ---- GRU + pooling ----
  gru_mfma_kernel<<<16, 512, 0, stream>>>(GI, WhhT_bf, bhh, GOUT, GOUT_bf);
  pool_a_kernel<<<256, 128, 0, stream>>>(h_iids, GOUT, W1, b1, LOCAL, Q1);
  linm_kernel<128, 32, false><<<100, 256, 0, stream>>>(
      GOUT_bf, W2T_bf, b2, Q2, nullptr, 12800);
  pool_b2_kernel<<<3200, 256, 0, stream>>>(Q2, Q1, W3, AL);
  pool_c_kernel<<<256, 128, 0, stream>>>(GOUT, AL, LOCAL, Wtr, btr, GHT_bf);

  // ---- logits ----
  logits_mfma_kernel<<<782, 256, 0, stream>>>(GHT_bf, (const ushort*)EMB_BF, out);
}

// Round 10
// 264.682 us; speedup vs baseline: 1.1491x; 1.0806x over previous
//
#include <hip/hip_runtime.h>
#include <hip/hip_bf16.h>
#include <math.h>

#define NB_B 256
#define NB_S 50
#define NB_NB 8
#define NB_D 128
#define NB_NITEMS 100000

typedef __attribute__((ext_vector_type(8))) short short8;   // 8 x bf16 (4 VGPR)
typedef __attribute__((ext_vector_type(4))) float f32x4;    // MFMA acc
typedef unsigned int uint;
typedef unsigned short ushort;

__device__ __forceinline__ float wave_sum(float t) {
#pragma unroll
  for (int off = 32; off; off >>= 1) t += __shfl_xor(t, off);
  return t;
}

__device__ __forceinline__ float sigf(float x) { return 1.f / (1.f + __expf(-x)); }

// fp32 -> bf16 round-to-nearest-even
__device__ __forceinline__ ushort f2bf(float f) {
  union { float f; uint u; } v;
  v.f = f;
  return (ushort)((v.u + 0x7fffu + ((v.u >> 16) & 1u)) >> 16);
}
__device__ __forceinline__ uint packbf(float a, float b) {
  return (uint)f2bf(a) | ((uint)f2bf(b) << 16);
}
__device__ __forceinline__ float bflo(uint u) {
  union { uint u; float f; } v; v.u = u << 16; return v.f;
}
__device__ __forceinline__ float bfhi(uint u) {
  union { uint u; float f; } v; v.u = u & 0xffff0000u; return v.f;
}

// ---------------- fused prep: EMB/REL casts + 4 weight transposes ----------------
// blockIdx ranges: [0,6250) EMB, [6250,6263) REL, [6263,6327) Wt,
// [6327,6519) Wih, [6519,6711) Whh, [6711,6775) W2.
__device__ __forceinline__ void castf_body(const float* __restrict__ src,
                                           uint* __restrict__ dst, int i, int n8) {
  if (i >= n8) return;
  float4 a = ((const float4*)src)[2 * i];
  float4 b = ((const float4*)src)[2 * i + 1];
  uint4 o;
  o.x = packbf(a.x, a.y);
  o.y = packbf(a.z, a.w);
  o.z = packbf(b.x, b.y);
  o.w = packbf(b.z, b.w);
  ((uint4*)dst)[i] = o;
}
template <int CO>
__device__ __forceinline__ void castT_body(const float* __restrict__ W,
                                           ushort* __restrict__ WT, int idx) {
  if (idx >= 128 * CO) return;
  int n = idx >> 7, k = idx & 127;
  WT[idx] = f2bf(W[(size_t)k * CO + n]);
}
__global__ __launch_bounds__(256) void prep_kernel(
    const float* __restrict__ item_emb, const float* __restrict__ rel_emb,
    const float* __restrict__ Wt, const float* __restrict__ Wih,
    const float* __restrict__ Whh, const float* __restrict__ W2,
    uint* __restrict__ EMB_BF, uint* __restrict__ REL_BF,
    ushort* __restrict__ WtT, ushort* __restrict__ WihT,
    ushort* __restrict__ WhhT, ushort* __restrict__ W2T) {
  int bx = blockIdx.x, tid = threadIdx.x;
  if (bx < 6250) {
    castf_body(item_emb, EMB_BF, bx * 256 + tid, 1600000);
  } else if (bx < 6263) {
    castf_body(rel_emb, REL_BF, (bx - 6250) * 256 + tid, 3200);
  } else if (bx < 6327) {
    castT_body<128>(Wt, WtT, (bx - 6263) * 256 + tid);
  } else if (bx < 6519) {
    castT_body<384>(Wih, WihT, (bx - 6327) * 256 + tid);
  } else if (bx < 6711) {
    castT_body<384>(Whh, WhhT, (bx - 6519) * 256 + tid);
  } else {
    castT_body<128>(W2, W2T, (bx - 6711) * 256 + tid);
  }
}

// ---------------- hop aggregation (bf16 tables, packed pairs) ----------------
template <int LEVEL>
__global__ __launch_bounds__(256) void hop_kernel(
    const int* __restrict__ h_iids, const int* __restrict__ adj_e,
    const int* __restrict__ adj_r, const uint* __restrict__ embB,
    const uint* __restrict__ relB, const uint* __restrict__ neibB,
    const float* __restrict__ Wa, uint* __restrict__ Xout, int npairs) {
  int p = (int)((blockIdx.x * blockDim.x + threadIdx.x) >> 6);
  p = __builtin_amdgcn_readfirstlane(p);
  int ln = threadIdx.x & 63;
  if (p >= npairs) return;

  int e_self;
  if (LEVEL == 0) {
    int b = p / (NB_S * NB_NB);
    int m = p % (NB_S * NB_NB);
    int s = m >> 3, j = m & 7;
    int h = h_iids[b * NB_S + s];
    e_self = adj_e[h * NB_NB + j];
  } else {
    e_self = h_iids[p];
  }

  float wa0 = Wa[2 * ln], wa1 = Wa[2 * ln + 1];
  uint us = embB[(size_t)e_self * 64 + ln];
  float s0 = bflo(us), s1 = bfhi(us);

  float nb0[NB_NB], nb1[NB_NB], att[NB_NB];
#pragma unroll
  for (int k = 0; k < NB_NB; k++) {
    int r = adj_r[e_self * NB_NB + k];
    uint un;
    if (LEVEL == 0) {
      int e2 = adj_e[e_self * NB_NB + k];
      un = embB[(size_t)e2 * 64 + ln];
    } else {
      un = neibB[((size_t)p * NB_NB + k) * 64 + ln];
    }
    uint ur = relB[r * 64 + ln];
    nb0[k] = bflo(un);
    nb1[k] = bfhi(un);
    float t = s0 * bflo(ur) * nb0[k] * wa0 + s1 * bfhi(ur) * nb1[k] * wa1;
    att[k] = wave_sum(t);
  }
  // |att| <= ~0.04 -> exp safe without max-subtraction (softmax-invariant)
  float den = 0.f, ex[NB_NB];
#pragma unroll
  for (int k = 0; k < NB_NB; k++) { ex[k] = __expf(att[k]); den += ex[k]; }
  float inv = 1.f / den;
  float x0 = s0, x1 = s1;
#pragma unroll
  for (int k = 0; k < NB_NB; k++) {
    float a = ex[k] * inv;
    x0 += a * nb0[k];
    x1 += a * nb1[k];
  }
  Xout[(size_t)p * 64 + ln] = packbf(x0, x1);
}

// ---------------- Y[N,CO] = Xbf[N,128] @ WT_bf^T + bias  (MFMA, no LDS) ----------------
template <int CO, int MPW, bool OUT_BF>
__global__ __launch_bounds__(256) void linm_kernel(
    const ushort* __restrict__ Xbf, const ushort* __restrict__ WT,
    const float* __restrict__ bias, float* __restrict__ Yf,
    ushort* __restrict__ Yb, int nrows) {
  constexpr int NF = CO / 16;
  constexpr int MF = MPW / 16;
  int wave = (int)(blockIdx.x * 4 + (threadIdx.x >> 6));
  int ln = threadIdx.x & 63;
  int m0 = __builtin_amdgcn_readfirstlane(wave) * MPW;
  if (m0 >= nrows) return;
  int lr = ln & 15, lg = ln >> 4;

  short8 afr[MF][4];
#pragma unroll
  for (int mf = 0; mf < MF; mf++) {
    const ushort* ab = Xbf + (size_t)(m0 + mf * 16 + lr) * 128 + lg * 8;
#pragma unroll
    for (int kf = 0; kf < 4; kf++) afr[mf][kf] = *(const short8*)(ab + kf * 32);
  }
  f32x4 acc[MF][NF] = {};
#pragma unroll
  for (int nf = 0; nf < NF; nf++) {
    const ushort* bb = WT + (size_t)(nf * 16 + lr) * 128 + lg * 8;
#pragma unroll
    for (int kf = 0; kf < 4; kf++) {
      short8 b = *(const short8*)(bb + kf * 32);
#pragma unroll
      for (int mf = 0; mf < MF; mf++)
        acc[mf][nf] = __builtin_amdgcn_mfma_f32_16x16x32_bf16(afr[mf][kf], b,
                                                              acc[mf][nf], 0, 0, 0);
    }
  }
#pragma unroll
  for (int mf = 0; mf < MF; mf++)
#pragma unroll
    for (int nf = 0; nf < NF; nf++) {
      int n = nf * 16 + lr;
      float bv = bias[n];
#pragma unroll
      for (int r = 0; r < 4; r++) {
        int m = m0 + mf * 16 + lg * 4 + r;
        float val = acc[mf][nf][r] + bv;
        if (OUT_BF)
          Yb[(size_t)m * CO + n] = f2bf(val);
        else
          Yf[(size_t)m * CO + n] = val;
      }
    }
}

// ---------------- GRU: lane-local gates, depth-3 pinned GI pipeline ----------------
// R9 post-mortem: depth-2 gave only -6us; suspect compiler SINKS the prefetch
// issue (plain loads are freely schedulable). Fix: depth-3 (4 named buffers,
// period-4 rotation) + sched_barrier(0) right after the issue block to PIN the
// 12 load issues at the top of step t (consumed at t+3). Barriers drain
// lgkmcnt only, so the loads stay in flight across them.
// NOTE: n-gate is tanh(inn + r*(gh_n + bhh_n)) -- bhh_n INSIDE the r* term.
__global__ __launch_bounds__(512) void gru_mfma_kernel(
    const float* __restrict__ GI, const ushort* __restrict__ WhhT_bf,
    const float* __restrict__ bhh, float* __restrict__ OUT,
    ushort* __restrict__ OUTB) {
  const int b0 = blockIdx.x * 16;
  const int tid = threadIdx.x;
  const int w = tid >> 6, ln = tid & 63;
  const int lr = ln & 15, lg = ln >> 4;
  const int j = w * 16 + lr;  // this lane's dim-column

  __shared__ ushort hA[16 * 128];  // XOR-swizzled bf16 h, double-buffered
  __shared__ ushort hB[16 * 128];

  // B-frags: gate g (0=r,1=z,2=n), cols n = g*128 + j
  short8 bfr[3][4];
#pragma unroll
  for (int g = 0; g < 3; g++) {
    const ushort* bb = WhhT_bf + (size_t)(g * 128 + j) * 128 + lg * 8;
#pragma unroll
    for (int kf = 0; kf < 4; kf++) bfr[g][kf] = *(const short8*)(bb + kf * 32);
  }

  float bh[3];
#pragma unroll
  for (int g = 0; g < 3; g++) bh[g] = bhh[g * 128 + j];

  float h_reg[4] = {0.f, 0.f, 0.f, 0.f};  // fp32 identity path, lane-local

  {  // zero hA (t=0 A operand)
    uint* hz = (uint*)hA;
#pragma unroll
    for (int i = tid; i < 1024; i += 512) hz[i] = 0;
  }
  __syncthreads();

  // GI register pipeline, depth 3: buf[t&3]; girX[r][g]=GI[b0+lg*4+r][t][g*128+j]
  float girA[4][3], girB[4][3], girC[4][3], girD[4][3];
#pragma unroll
  for (int r = 0; r < 4; r++) {
    const float* g0 = GI + ((size_t)(b0 + lg * 4 + r) * NB_S + 0) * 384 + j;
    girA[r][0] = g0[0]; girA[r][1] = g0[128]; girA[r][2] = g0[256];
    const float* g1 = GI + ((size_t)(b0 + lg * 4 + r) * NB_S + 1) * 384 + j;
    girB[r][0] = g1[0]; girB[r][1] = g1[128]; girB[r][2] = g1[256];
    const float* g2 = GI + ((size_t)(b0 + lg * 4 + r) * NB_S + 2) * 384 + j;
    girC[r][0] = g2[0]; girC[r][1] = g2[128]; girC[r][2] = g2[256];
  }

  auto STEP = [&](int t, ushort* hRead, ushort* hWrite, float (&cur)[4][3],
                  float (&pre3)[4][3]) {
    // issue GI loads for t+3 FIRST, then PIN the issue point
    if (t + 3 < NB_S) {
#pragma unroll
      for (int r = 0; r < 4; r++) {
        const float* g = GI + ((size_t)(b0 + lg * 4 + r) * NB_S + (t + 3)) * 384 + j;
        pre3[r][0] = g[0]; pre3[r][1] = g[128]; pre3[r][2] = g[256];
      }
    }
    __builtin_amdgcn_sched_barrier(0);  // pin load issue at top of step
    // A-frags from swizzled hRead
    short8 afr[4];
#pragma unroll
    for (int kf = 0; kf < 4; kf++) {
      int byte = (lr * 256 + kf * 64 + lg * 16) ^ ((lr & 7) << 4);
      afr[kf] = *(const short8*)((const char*)hRead + byte);
    }
    f32x4 acc[3] = {};
#pragma unroll
    for (int g = 0; g < 3; g++)
#pragma unroll
      for (int kf = 0; kf < 4; kf++)
        acc[g] = __builtin_amdgcn_mfma_f32_16x16x32_bf16(afr[kf], bfr[g][kf],
                                                         acc[g], 0, 0, 0);
    // gates: all operands lane-local
#pragma unroll
    for (int r = 0; r < 4; r++) {
      int b = lg * 4 + r;
      float rg = sigf(cur[r][0] + bh[0] + acc[0][r]);
      float zg = sigf(cur[r][1] + bh[1] + acc[1][r]);
      float x = cur[r][2] + rg * (bh[2] + acc[2][r]);  // bias INSIDE r*
      float e2 = __expf(2.f * x);
      float n = 1.f - 2.f / (e2 + 1.f);  // tanh(x)
      float h2 = (1.f - zg) * n + zg * h_reg[r];
      h_reg[r] = h2;
      size_t o = ((size_t)(b0 + b) * NB_S + t) * 128 + j;
      OUT[o] = h2;
      ushort hb = f2bf(h2);
      OUTB[o] = hb;
      int byte = (b * 256 + j * 2) ^ ((b & 7) << 4);
      *(ushort*)((char*)hWrite + byte) = hb;
    }
    asm volatile("s_waitcnt lgkmcnt(0)" ::: "memory");
    __builtin_amdgcn_s_barrier();  // hWrite visible; global loads stay in flight
  };

  // 48 steps in 12 groups of 4 (buffer rotation period 4), then 2 peeled.
  for (int g4 = 0; g4 < 12; g4++) {
    int t = g4 * 4;  // t % 4 == 0 (even)
    STEP(t + 0, hA, hB, girA, girD);
    STEP(t + 1, hB, hA, girB, girA);
    STEP(t + 2, hA, hB, girC, girB);
    STEP(t + 3, hB, hA, girD, girC);
  }
  STEP(48, hA, hB, girA, girD);  // loads for t=51 skipped
  STEP(49, hB, hA, girB, girA);
}

// ---------------- fused pooling: local_ht/Q1 + Q2(MFMA) + AL + global/GHT ----------------
// 256 blocks (one per batch), 256 threads (4 waves).
__global__ __launch_bounds__(256) void pool_kernel(
    const int* __restrict__ h_iids, const float* __restrict__ OUT,
    const ushort* __restrict__ OUTB, const float* __restrict__ W1,
    const float* __restrict__ b1, const ushort* __restrict__ W2T,
    const float* __restrict__ b2, const float* __restrict__ W3,
    const float* __restrict__ Wtr, const float* __restrict__ btr,
    ushort* __restrict__ GHT_bf) {
  const int b = blockIdx.x, tid = threadIdx.x;
  __shared__ float lh[128];
  __shared__ float q1[128];
  __shared__ float al[64];
  __shared__ float cat[256];

  // phase 1a: last index + local_ht
  if (tid < 128) {
    int cnt = 0;
    for (int s = 0; s < NB_S; s++) cnt += (h_iids[b * NB_S + s] != 0);
    int li = min(max(cnt - 1, 0), NB_S - 1);
    lh[tid] = OUT[((size_t)b * NB_S + li) * 128 + tid];
  }
  __syncthreads();
  // phase 1b: Q1 = local_ht @ W1 + b1
  if (tid < 128) {
    float acc = b1[tid];
    for (int d = 0; d < 128; d++) acc += lh[d] * W1[(size_t)d * 128 + tid];
    q1[tid] = acc;
  }
  __syncthreads();

  // phase 2: Q2 rows via MFMA (wave wv covers s in [16wv,16wv+16)), then
  // al[s] = sum_c sig(q1[c]+q2[s][c]+b2[c])*W3[c] reduced across lr lanes.
  {
    const int wv = tid >> 6, ln = tid & 63, lr = ln & 15, lg = ln >> 4;
    const int s0 = wv * 16;
    short8 zz = {0, 0, 0, 0, 0, 0, 0, 0};
    short8 afr[4];
    int srow = s0 + lr;
#pragma unroll
    for (int kf = 0; kf < 4; kf++)
      afr[kf] = (srow < NB_S)
                    ? *(const short8*)(OUTB + ((size_t)b * NB_S + srow) * 128 +
                                       lg * 8 + kf * 32)
                    : zz;
    float part[4] = {0.f, 0.f, 0.f, 0.f};
#pragma unroll
    for (int nf = 0; nf < 8; nf++) {
      const ushort* bb = W2T + (size_t)(nf * 16 + lr) * 128 + lg * 8;
      f32x4 acc = {};
#pragma unroll
      for (int kf = 0; kf < 4; kf++) {
        short8 bv = *(const short8*)(bb + kf * 32);
        acc = __builtin_amdgcn_mfma_f32_16x16x32_bf16(afr[kf], bv, acc, 0, 0, 0);
      }
      int c = nf * 16 + lr;
      float qc = q1[c] + b2[c];
      float w3 = W3[c];
#pragma unroll
      for (int r = 0; r < 4; r++) part[r] += sigf(qc + acc[r]) * w3;
    }
    // reduce across the 16 lr-lanes (same lg): xor 1,2,4,8
#pragma unroll
    for (int r = 0; r < 4; r++) {
#pragma unroll
      for (int off = 1; off < 16; off <<= 1) part[r] += __shfl_xor(part[r], off);
      int s = s0 + lg * 4 + r;
      if (lr == 0 && s < NB_S) al[s] = part[r];
    }
  }
  __syncthreads();

  // phase 3: global_ht + GHT = [local, global] @ Wtr + btr (bf16 out)
  if (tid < 128) {
    float g = 0.f;
    for (int s = 0; s < NB_S; s++)
      g += al[s] * OUT[((size_t)b * NB_S + s) * 128 + tid];
    cat[tid] = lh[tid];
    cat[128 + tid] = g;
  }
  __syncthreads();
  if (tid < 128) {
    float acc = btr[tid];
    for (int dd = 0; dd < 256; dd++) acc += cat[dd] * Wtr[(size_t)dd * 128 + tid];
    GHT_bf[b * 128 + tid] = f2bf(acc);
  }
}

// ---------------- logits = relu(GHT_bf @ EMB_BF^T) via MFMA ----------------
__global__ __launch_bounds__(256) void logits_mfma_kernel(
    const ushort* __restrict__ GHT_bf, const ushort* __restrict__ embB,
    float* __restrict__ out) {
  int wave = (int)(blockIdx.x * 4 + (threadIdx.x >> 6));
  int ln = threadIdx.x & 63;
  int n0 = __builtin_amdgcn_readfirstlane(wave) * 32;
  if (n0 >= NB_NITEMS) return;
  int lr = ln & 15, lg = ln >> 4;

  short8 bfr[2][4];
#pragma unroll
  for (int nf = 0; nf < 2; nf++) {
    const ushort* base = embB + (size_t)(n0 + nf * 16 + lr) * 128 + lg * 8;
#pragma unroll
    for (int kf = 0; kf < 4; kf++) bfr[nf][kf] = *(const short8*)(base + kf * 32);
  }

  f32x4 acc[16][2] = {};
#pragma unroll
  for (int mg = 0; mg < 4; mg++) {
    short8 afr[4][4];
#pragma unroll
    for (int mf = 0; mf < 4; mf++) {
      const ushort* ab = GHT_bf + (size_t)((mg * 4 + mf) * 16 + lr) * 128 + lg * 8;
#pragma unroll
      for (int kf = 0; kf < 4; kf++) afr[mf][kf] = *(const short8*)(ab + kf * 32);
    }
#pragma unroll
    for (int mf = 0; mf < 4; mf++)
#pragma unroll
      for (int nf = 0; nf < 2; nf++)
#pragma unroll
        for (int kf = 0; kf < 4; kf++)
          acc[mg * 4 + mf][nf] = __builtin_amdgcn_mfma_f32_16x16x32_bf16(
              afr[mf][kf], bfr[nf][kf], acc[mg * 4 + mf][nf], 0, 0, 0);
  }

#pragma unroll
  for (int mf = 0; mf < 16; mf++)
#pragma unroll
    for (int nf = 0; nf < 2; nf++) {
      int n = n0 + nf * 16 + lr;
#pragma unroll
      for (int r = 0; r < 4; r++) {
        int m = mf * 16 + lg * 4 + r;
        out[(size_t)m * NB_NITEMS + n] = fmaxf(acc[mf][nf][r], 0.f);
      }
    }
}

extern "C" void kernel_launch(void* const* d_in, const int* in_sizes, int n_in,
                              void* d_out, int out_size, void* d_ws, size_t ws_size,
                              hipStream_t stream) {
  const int* h_iids = (const int*)d_in[0];
  const int* adj_e = (const int*)d_in[2];
  const int* adj_r = (const int*)d_in[3];
  const float* item_emb = (const float*)d_in[4];
  const float* rel_emb = (const float*)d_in[5];
  const float* Wa = (const float*)d_in[6];
  const float* Wt = (const float*)d_in[8];
  const float* bt = (const float*)d_in[9];
  const float* Wih = (const float*)d_in[10];
  const float* Whh = (const float*)d_in[11];
  const float* bih = (const float*)d_in[12];
  const float* bhh = (const float*)d_in[13];
  const float* W1 = (const float*)d_in[14];
  const float* b1 = (const float*)d_in[15];
  const float* W2 = (const float*)d_in[16];
  const float* b2 = (const float*)d_in[17];
  const float* W3 = (const float*)d_in[18];
  const float* Wtr = (const float*)d_in[19];
  const float* btr = (const float*)d_in[20];
  float* out = (float*)d_out;

  // ws layout (bytes), all 16B-aligned. ~85 MB total.
  char* w = (char*)d_ws;
  uint* EMB_BF = (uint*)w;                    w += 25600000;  // 100000x128 bf16
  uint* REL_BF = (uint*)w;                    w += 51200;     // 200x128 bf16
  ushort* WtT_bf = (ushort*)w;                w += 32768;     // [128][128]
  ushort* WihT_bf = (ushort*)w;               w += 98304;     // [384][128]
  ushort* WhhT_bf = (ushort*)w;               w += 98304;     // [384][128]
  ushort* W2T_bf = (ushort*)w;                w += 32768;     // [128][128]
  uint* NEIB_bf = (uint*)w;                   w += 26214400;  // 102400x128 bf16
  uint* X1_bf = (uint*)w;                     w += 3276800;   // 12800x128 bf16
  uint* SEQ_bf = (uint*)w;                    w += 3276800;   // 12800x128 bf16
  float* GI = (float*)w;                      w += 19660800;  // 12800x384 fp32
  float* GOUT = (float*)w;                    w += 6553600;   // 12800x128 fp32
  ushort* GHT_bf = (ushort*)w;                w += 65536;

  // Aliases into dead regions (recomputed every launch -> replay-safe):
  uint* X0_bf = (uint*)d_out;                 // hop0 out; logits overwrites d_out
  ushort* GOUT_bf = (ushort*)X1_bf;           // X1_bf dead after SEQ GEMM

  // ---- fused prep casts (1 launch) ----
  prep_kernel<<<6775, 256, 0, stream>>>(item_emb, rel_emb, Wt, Wih, Whh, W2,
                                        EMB_BF, REL_BF, WtT_bf, WihT_bf,
                                        WhhT_bf, W2T_bf);

  // ---- KG hops ----
  hop_kernel<0><<<25600, 256, 0, stream>>>(h_iids, adj_e, adj_r, EMB_BF, REL_BF,
                                           nullptr, Wa, X0_bf, 102400);
  linm_kernel<128, 32, true><<<800, 256, 0, stream>>>(
      (const ushort*)X0_bf, WtT_bf, bt, nullptr, (ushort*)NEIB_bf, 102400);
  hop_kernel<1><<<3200, 256, 0, stream>>>(h_iids, adj_e, adj_r, EMB_BF, REL_BF,
                                          NEIB_bf, Wa, X1_bf, 12800);
  linm_kernel<128, 32, true><<<100, 256, 0, stream>>>(
      (const ushort*)X1_bf, WtT_bf, bt, nullptr, (ushort*)SEQ_bf, 12800);
  linm_kernel<384, 16, false><<<200, 256, 0, stream>>>(
      (const ushort*)SEQ_bf, WihT_bf, bih, GI, nullptr, 12800);

  // ---- GRU + fused pooling ----
  gru_mfma_kernel<<<16, 512, 0, stream>>>(GI, WhhT_bf, bhh, GOUT, GOUT_bf);
  pool_kernel<<<256, 256, 0, stream>>>(h_iids, GOUT, GOUT_bf, W1, b1, W2T_bf,
                                       b2, W3, Wtr, btr, GHT_bf);

  // ---- logits ----
  logits_mfma_kernel<<<782, 256, 0, stream>>>(GHT_bf, (const ushort*)EMB_BF, out);
}